// Round 1
// baseline (210.401 us; speedup 1.0000x reference)
//
#include <hip/hip_runtime.h>

// ---------------------------------------------------------------------------
// DualAttention on MI355X.  B=8 L=8 C=64 W=32 (WH=1024, LWH=8192) NH=128 FS=5
// R8: k2 occupancy fix.  Spatial branch restructured to kv-half P staging:
//   per 64-kv iter, do {S(n=2h,2h+1) -> P-half -> PV(ks=h)} for h=0,1.
//   Pl shrinks 32KB->20KB (64x40-padded rows, 16B-aligned, conflict-floor;
//   replaces the old XOR swizzle).  LDS 64KB->52KB => 3 blocks/CU and the
//   whole 640-block grid co-resident (768 slots) -- no second-round tail.
// Everything else unchanged vs R7.
// ---------------------------------------------------------------------------

#define LOG2E 1.44269504088896340736f

typedef __attribute__((ext_vector_type(8))) short short8;   // bf16 x8 frag
typedef __attribute__((ext_vector_type(4))) float f4;       // fp32 x4 frag

#define MFMA16(a, b, c) __builtin_amdgcn_mfma_f32_16x16x32_bf16(a, b, c, 0, 0, 0)

#define GLOAD_LDS16(gp, lp) __builtin_amdgcn_global_load_lds( \
    (const __attribute__((address_space(1))) void*)(gp), \
    (__attribute__((address_space(3))) void*)(lp), 16, 0, 0)

__device__ __forceinline__ unsigned short f2bf(float f) {   // RNE float->bf16
  union { float f; unsigned u; } v; v.f = f;
  unsigned r = v.u + 0x7FFFu + ((v.u >> 16) & 1u);
  return (unsigned short)(r >> 16);
}
__device__ __forceinline__ unsigned short f2bf_rz(float f) { // truncate (P only)
  union { float f; unsigned u; } v; v.f = f;
  return (unsigned short)(v.u >> 16);
}
__device__ __forceinline__ float bf2f(unsigned short h) {
  union { unsigned u; float f; } v; v.u = ((unsigned)h) << 16;
  return v.f;
}
__device__ __forceinline__ float exp2fast(float x) {
#if __has_builtin(__builtin_amdgcn_exp2f)
  return __builtin_amdgcn_exp2f(x);
#else
  return exp2f(x);
#endif
}

// ---------------- workspace layout (bytes), total ~45.0MB ------------------
#define O_STATS 0ul                      // [2][8][2] f32 (memset 0)
#define O_W1T   256ul                    // [2][25][64][64] bf16
#define O_W2B   409856ul                 // [2][128][64] bf16
#define O_LNW   442624ul                 // [2][1024][64] bf16 (transposed lnw)
#define O_LNB   704768ul                 // [2][1024][64] bf16
#define O_QT    966912ul                 // [8][1024][64] bf16  q^T
#define O_KSP   2015488ul                // [8][8192][64] bf16  spatial K *LOG2E
#define O_VT    10404096ul               // [8][64][8192] bf16  spatial V^T
#define O_NUM   18792704ul               // [8][1024][16][64] bf16 spat num part
#define O_DEN   35569920ul               // [8][1024][16] f32      spat den part
#define O_SP    36094208ul               // [4][8][64][512] f32 chan S partials
#define O_PCH   40288512ul               // [8][64][512] bf16   chan P
#define O_XS    40812800ul               // [8][1024][64] bf16 stem in (spatial)
#define O_XC    41861376ul               // [8][1024][64] bf16 stem in (channel)
#define O_YT    42909952ul               // [2][8][1024][64] bf16 conv1 out

// ============================================================================
// K1: tile transposes + LN transposes + weights.  grid 3104.
// ============================================================================
__global__ __launch_bounds__(256) void k1_prep(
    const float* __restrict__ q, const float* __restrict__ keys,
    const float* __restrict__ values,
    const float* __restrict__ sw1, const float* __restrict__ slnw,
    const float* __restrict__ slnb, const float* __restrict__ sw2,
    const float* __restrict__ cw1, const float* __restrict__ clnw,
    const float* __restrict__ clnb, const float* __restrict__ cw2,
    char* __restrict__ ws)
{
  __shared__ float T[64][65];
  const int job = blockIdx.x, t = threadIdx.x;

  if (job < 2240) {                      // ---- tile jobs ----
    int kind, mat = 0, sel = 0;
    if (job < 1024)      { kind = 0; mat = job >> 4; }
    else if (job < 2048) { kind = 1; mat = (job - 1024) >> 4; }
    else if (job < 2176) { kind = 2; mat = (job - 2048) >> 4; }
    else                 { kind = 3; sel = (job - 2176) >> 4; }
    const int pt = job & 15, p0 = pt * 64;
    const float* src =
        kind == 0 ? keys : kind == 1 ? values : kind == 2 ? q
        : (sel == 0 ? slnw : sel == 1 ? slnb : sel == 2 ? clnw : clnb);
    src += (size_t)mat * 65536;

    const int r0 = t >> 4, c4 = (t & 15) * 4;
    if (kind == 1) {                     // identity only: V^T[b][c][l*1024+p]
      unsigned short* VTp = (unsigned short*)(ws + O_VT);
      const int b = mat >> 3, l = mat & 7;
#pragma unroll
      for (int pass = 0; pass < 4; ++pass) {
        const int r = pass * 16 + r0;
        float4 v = *(const float4*)(src + (size_t)r * 1024 + p0 + c4);
        ushort4 o;
        o.x = f2bf(v.x); o.y = f2bf(v.y); o.z = f2bf(v.z); o.w = f2bf(v.w);
        *(ushort4*)(VTp + ((size_t)b * 64 + r) * 8192 + l * 1024 + p0 + c4) = o;
      }
      return;
    }
#pragma unroll
    for (int pass = 0; pass < 4; ++pass) {
      const int r = pass * 16 + r0;
      float4 v = *(const float4*)(src + (size_t)r * 1024 + p0 + c4);
      T[r][c4] = v.x; T[r][c4 + 1] = v.y; T[r][c4 + 2] = v.z; T[r][c4 + 3] = v.w;
    }
    __syncthreads();
#pragma unroll
    for (int pass = 0; pass < 2; ++pass) {
      const int p = pass * 32 + (t >> 3), cs = (t & 7) * 8;
      short8 o;
      if (kind == 0) {                   // Ksp[b][l*1024+p][c] * LOG2E
#pragma unroll
        for (int j = 0; j < 8; ++j) o[j] = (short)f2bf(T[cs + j][p] * LOG2E);
        const int b = mat >> 3, l = mat & 7;
        *(short8*)((unsigned short*)(ws + O_KSP) +
                   ((size_t)b * 8192 + l * 1024 + p0 + p) * 64 + cs) = o;
      } else if (kind == 2) {            // Qt[b][p][c]
#pragma unroll
        for (int j = 0; j < 8; ++j) o[j] = (short)f2bf(T[cs + j][p]);
        *(short8*)((unsigned short*)(ws + O_QT) +
                   ((size_t)mat * 1024 + p0 + p) * 64 + cs) = o;
      } else {                           // LN param^T [s][p][c]
#pragma unroll
        for (int j = 0; j < 8; ++j) o[j] = (short)f2bf(T[cs + j][p]);
        unsigned long off = (sel & 1) ? O_LNB : O_LNW;
        *(short8*)((unsigned short*)(ws + off) +
                   ((size_t)(sel >> 1) * 1024 + p0 + p) * 64 + cs) = o;
      }
    }
    return;
  }

  // ---- weights ----
  {
    unsigned i = (job - 2240) * 256u + t;
    if (i < 204800u) {                   // W1t[s][off][co][ci] <- w1[co][ci][off]
      unsigned ci = i & 63u, co = (i >> 6) & 63u, tt = i >> 12;
      unsigned off = tt % 25u, st = tt / 25u;
      const float* w = st ? cw1 : sw1;
      ((unsigned short*)(ws + O_W1T))[i] = f2bf(w[(co * 64u + ci) * 25u + off]);
      return;
    }
    i -= 204800u;
    if (i < 16384u) {                    // W2b[s][nh][c]
      unsigned c = i & 63u, nh = (i >> 6) & 127u, st = i >> 13;
      const float* w = st ? cw2 : sw2;
      ((unsigned short*)(ws + O_W2B))[i] = f2bf(w[nh * 64u + c]);
    }
  }
}

// ============================================================================
// K2: spat_attn (blocks 0..511) ∪ chan_S (512..639)
// spat: M=4, lane-linear frag staging, dbuf, den-MFMA, kv-split 16; P staged
//   per kv-half in padded-row LDS (64x40 ushort) -> 52KB total, 3 blocks/CU.
// chan_S: (b:8)x(colT:4 of 128 cols)x(kt:4 of 256 k).  Per iter (32 k):
//   stage raw f32 K-tile[128x32] + Q-tile[64x32] via global_load_lds into
//   frag-chunk order (dbuf 48KB); hi/lo split from LDS; 24 MFMA/wave/iter.
// ============================================================================
__global__ __launch_bounds__(256) void k2_spat_chanS(
    const float* __restrict__ q, const float* __restrict__ keys,
    char* __restrict__ ws)
{
  __shared__ __align__(16) unsigned char SM[53248];

  if (blockIdx.x < 512) {                // ================= spatial =========
    unsigned short (*Kt)[4096] = (unsigned short(*)[4096])(SM);
    unsigned short (*Vt)[4096] = (unsigned short(*)[4096])(SM + 16384);
    // Pl: per-wave P half-tile, 64 rows x 32 kv, rows padded to 40 ushorts
    // (80B = 16B-aligned, bank-floor on b128 reads, 2-way-free on writes)
    unsigned short (*Pl)[2560] = (unsigned short(*)[2560])(SM + 32768);

    const unsigned short* QT = (const unsigned short*)(ws + O_QT);
    const unsigned short* KSP = (const unsigned short*)(ws + O_KSP);
    const unsigned short* VTg = (const unsigned short*)(ws + O_VT);
    unsigned short* NUM = (unsigned short*)(ws + O_NUM);
    float* DEN = (float*)(ws + O_DEN);

    const int b = blockIdx.x >> 6;
    const int qt = (blockIdx.x >> 4) & 3;
    const int s = blockIdx.x & 15;
    const int t = threadIdx.x;
    const int w = t >> 6, lane = t & 63;
    const int low4 = lane & 15, quad = lane >> 4;

    const unsigned short* KSPb = KSP + (size_t)b * 8192 * 64;
    const unsigned short* VTb = VTg + (size_t)b * 64 * 8192;
    const int qbase = qt * 256 + w * 64;
    const int kvbase = s * 512;

    int cn[2], cks[2], cqd[2], cl4[2];
#pragma unroll
    for (int pass = 0; pass < 2; ++pass) {
      const int c = pass * 256 + t;
      cn[pass] = c >> 7; cks[pass] = (c >> 6) & 1;
      cqd[pass] = (c >> 4) & 3; cl4[pass] = c & 15;
    }

    short8 qa[4][2];
#pragma unroll
    for (int mi = 0; mi < 4; ++mi)
#pragma unroll
      for (int ks = 0; ks < 2; ++ks)
        qa[mi][ks] = *(const short8*)(QT +
            ((size_t)(b * 1024 + qbase + mi * 16 + low4)) * 64 + ks * 32 + quad * 8);

    short8 vones;
#pragma unroll
    for (int j = 0; j < 8; ++j) vones[j] = (short)0x3F80;

    f4 accO[4][4], accD[4];
#pragma unroll
    for (int m = 0; m < 4; ++m) {
      accD[m] = (f4){0.f, 0.f, 0.f, 0.f};
#pragma unroll
      for (int n = 0; n < 4; ++n) accO[m][n] = (f4){0.f, 0.f, 0.f, 0.f};
    }

#pragma unroll
    for (int pass = 0; pass < 2; ++pass) {
      GLOAD_LDS16(KSPb + ((size_t)(kvbase + cn[pass] * 16 + cl4[pass])) * 64 +
                      cks[pass] * 32 + cqd[pass] * 8,
                  &Kt[0][(pass * 256 + w * 64) * 8]);
      GLOAD_LDS16(VTb + ((size_t)(cn[pass] * 16 + cl4[pass])) * 8192 + kvbase +
                      cks[pass] * 32 + cqd[pass] * 8,
                  &Vt[0][(pass * 256 + w * 64) * 8]);
    }

    for (int it = 0; it < 8; ++it) {
      const int d = it & 1;
      __syncthreads();
      if (it < 7) {
        const int kv1 = kvbase + (it + 1) * 64;
#pragma unroll
        for (int pass = 0; pass < 2; ++pass) {
          GLOAD_LDS16(KSPb + ((size_t)(kv1 + cn[pass] * 16 + cl4[pass])) * 64 +
                          cks[pass] * 32 + cqd[pass] * 8,
                      &Kt[d ^ 1][(pass * 256 + w * 64) * 8]);
          GLOAD_LDS16(VTb + ((size_t)(cn[pass] * 16 + cl4[pass])) * 8192 + kv1 +
                          cks[pass] * 32 + cqd[pass] * 8,
                      &Vt[d ^ 1][(pass * 256 + w * 64) * 8]);
        }
      }
#pragma unroll
      for (int h = 0; h < 2; ++h) {
        // ---- S for this kv-half (32 cols), straight into padded P half ----
#pragma unroll
        for (int nl = 0; nl < 2; ++nl) {
          const int n = h * 2 + nl;
          f4 sS[4];
#pragma unroll
          for (int mi = 0; mi < 4; ++mi) sS[mi] = (f4){0.f, 0.f, 0.f, 0.f};
#pragma unroll
          for (int ks = 0; ks < 2; ++ks) {
            short8 kb = *(const short8*)&Kt[d][((n * 2 + ks) * 64 + lane) * 8];
#pragma unroll
            for (int mi = 0; mi < 4; ++mi) sS[mi] = MFMA16(qa[mi][ks], kb, sS[mi]);
          }
#pragma unroll
          for (int mi = 0; mi < 4; ++mi) {
            unsigned short* pw = &Pl[w][(mi * 16 + quad * 4) * 40 + nl * 16 + low4];
#pragma unroll
            for (int r = 0; r < 4; ++r)
              pw[r * 40] = f2bf_rz(exp2fast(sS[mi][r]));
          }
        }
        // ---- PV for this kv-half (ks = h) ----
        short8 vb[4];
#pragma unroll
        for (int n2 = 0; n2 < 4; ++n2)
          vb[n2] = *(const short8*)&Vt[d][((n2 * 2 + h) * 64 + lane) * 8];
#pragma unroll
        for (int m = 0; m < 4; ++m) {
          short8 pa = *(const short8*)&Pl[w][(m * 16 + low4) * 40 + quad * 8];
          accD[m] = MFMA16(pa, vones, accD[m]);
#pragma unroll
          for (int n2 = 0; n2 < 4; ++n2) accO[m][n2] = MFMA16(pa, vb[n2], accO[m][n2]);
        }
      }
    }

#pragma unroll
    for (int m = 0; m < 4; ++m)
#pragma unroll
      for (int r = 0; r < 4; ++r) {
        const int row = qbase + m * 16 + quad * 4 + r;
        const size_t base = ((size_t)(b * 1024 + row) * 16 + s);
#pragma unroll
        for (int n2 = 0; n2 < 4; ++n2)
          NUM[base * 64 + n2 * 16 + low4] = f2bf(accO[m][n2][r]);
        if (low4 == 0) DEN[base] = accD[m][r];
      }
    return;
  }

  // ================= chan_S =================
  {
    float* Sp = (float*)(ws + O_SP);
    const int bid = blockIdx.x - 512;
    const int b = bid >> 4, colT = (bid >> 2) & 3, kt = bid & 3;
    const int t = threadIdx.x, w = t >> 6, lane = t & 63;
    const int low4 = lane & 15, quad = lane >> 4;
    const int dl = lane >> 1, dh = lane & 1;
    const int k00 = kt * 256;

    // buf layout (per buf, 24576B): K f32 tile at +0 (16KB), Q at +16384 (8KB)
    f4 acc[4][2];
#pragma unroll
    for (int m = 0; m < 4; ++m)
#pragma unroll
      for (int n = 0; n < 2; ++n) acc[m][n] = (f4){0.f, 0.f, 0.f, 0.f};

    // stage one iter's tiles into buf at byte offset bo (6 DMA instrs/thread)
    auto stageAll = [&](int bo, int k0) {
#pragma unroll
      for (int gi = 0; gi < 4; ++gi) {           // K: groups w, w+4, w+8, w+12
        const int g = w + gi * 4;
        const int n = g >> 1, sub = g & 1;
        const int l = sub * 32 + dl;
        const float* gp = keys + (size_t)(b * 512 + colT * 128 + n * 16 + (l & 15)) * 1024
                          + k0 + (l >> 4) * 8 + dh * 4;
        GLOAD_LDS16(gp, SM + bo + (size_t)(n * 128 + sub * 64) * 16);
      }
#pragma unroll
      for (int gi = 0; gi < 2; ++gi) {           // Q: groups w, w+4
        const int g = w + gi * 4;
        const int m = g >> 1, sub = g & 1;
        const int l = sub * 32 + dl;
        const float* gp = q + (size_t)(b * 64 + m * 16 + (l & 15)) * 1024
                          + k0 + (l >> 4) * 8 + dh * 4;
        GLOAD_LDS16(gp, SM + bo + 16384 + (size_t)(m * 128 + sub * 64) * 16);
      }
    };

    stageAll(0, k00);
    for (int it = 0; it < 8; ++it) {
      const int bo = (it & 1) * 24576;
      const char* cb = (const char*)SM + bo;
      __syncthreads();
      if (it < 7) stageAll(bo ^ 24576, k00 + (it + 1) * 32);

      short8 ah[4], al[4];
#pragma unroll
      for (int m = 0; m < 4; ++m) {              // A-frags from LDS, *LOG2E, split
        const float* fp = (const float*)(cb + 16384 + (size_t)(m * 128 + lane * 2) * 16);
        float4 u0 = ((const float4*)fp)[0];
        float4 u1 = ((const float4*)fp)[1];
        float vv[8] = {u0.x, u0.y, u0.z, u0.w, u1.x, u1.y, u1.z, u1.w};
#pragma unroll
        for (int j = 0; j < 8; ++j) {
          float sv = vv[j] * LOG2E;
          unsigned short hi = f2bf(sv);
          ah[m][j] = (short)hi;
          al[m][j] = (short)f2bf(sv - bf2f(hi));
        }
      }
#pragma unroll
      for (int n2 = 0; n2 < 2; ++n2) {           // B-frags (this wave's 2 n-tiles)
        const int n = w * 2 + n2;
        const float* fp = (const float*)(cb + (size_t)(n * 128 + lane * 2) * 16);
        float4 u0 = ((const float4*)fp)[0];
        float4 u1 = ((const float4*)fp)[1];
        float vv[8] = {u0.x, u0.y, u0.z, u0.w, u1.x, u1.y, u1.z, u1.w};
        short8 bh, bl;
#pragma unroll
        for (int j = 0; j < 8; ++j) {
          unsigned short hi = f2bf(vv[j]);
          bh[j] = (short)hi;
          bl[j] = (short)f2bf(vv[j] - bf2f(hi));
        }
#pragma unroll
        for (int m = 0; m < 4; ++m) {
          acc[m][n2] = MFMA16(ah[m], bh, acc[m][n2]);
          acc[m][n2] = MFMA16(al[m], bh, acc[m][n2]);
          acc[m][n2] = MFMA16(ah[m], bl, acc[m][n2]);
        }
      }
    }

#pragma unroll
    for (int m = 0; m < 4; ++m)
#pragma unroll
      for (int n2 = 0; n2 < 2; ++n2)
#pragma unroll
        for (int r = 0; r < 4; ++r) {
          const int row = m * 16 + quad * 4 + r;
          const int col = colT * 128 + (w * 2 + n2) * 16 + low4;
          Sp[(((size_t)kt * 8 + b) * 64 + row) * 512 + col] = acc[m][n2][r];
        }
  }
}

// ============================================================================
// K3: spat_fin (blocks 0..511) ∪ chan_soft (512..543)
// ============================================================================
__global__ __launch_bounds__(256) void k3_fin_soft(char* __restrict__ ws)
{
  if (blockIdx.x < 512) {                // ---- spat_fin: 16 bf16 partials ----
    const unsigned short* NUM = (const unsigned short*)(ws + O_NUM);
    const float* DEN = (const float*)(ws + O_DEN);
    const unsigned short* QT = (const unsigned short*)(ws + O_QT);
    unsigned short* Xs = (unsigned short*)(ws + O_XS);

    const unsigned i = blockIdx.x * 256u + threadIdx.x;   // 131072
    const int c0 = (i & 15) * 4;
    const unsigned row = i >> 4;                          // [0, 8192)

    float dtot = 0.f;
#pragma unroll
    for (int sq = 0; sq < 4; ++sq) {
      float4 dv = *(const float4*)(DEN + (size_t)row * 16 + sq * 4);
      dtot += dv.x + dv.y + dv.z + dv.w;
    }
    float n4[4] = {0.f, 0.f, 0.f, 0.f};
#pragma unroll
    for (int s = 0; s < 16; ++s) {
      ushort4 pv = *(const ushort4*)(NUM + ((size_t)row * 16 + s) * 64 + c0);
      n4[0] += bf2f(pv.x); n4[1] += bf2f(pv.y);
      n4[2] += bf2f(pv.z); n4[3] += bf2f(pv.w);
    }
    const float rd = 1.0f / dtot;
    size_t ob = (size_t)row * 64 + c0;
    ushort4 qv = *(const ushort4*)(QT + ob);
    ushort4 o4;
    o4.x = f2bf(n4[0] * rd + bf2f(qv.x));
    o4.y = f2bf(n4[1] * rd + bf2f(qv.y));
    o4.z = f2bf(n4[2] * rd + bf2f(qv.z));
    o4.w = f2bf(n4[3] * rd + bf2f(qv.w));
    *(ushort4*)(Xs + ob) = o4;
    return;
  }

  // ---- chan_soft: sum 4 partials, max-sub, exp2, normalize -> P ----
  {
    const float* Sp = (const float*)(ws + O_SP);
    unsigned short* P = (unsigned short*)(ws + O_PCH);
    const int bid = blockIdx.x - 512;
    const int b = bid >> 2, rt = bid & 3;
    const int row = rt * 16 + (threadIdx.x >> 4), tc = threadIdx.x & 15;

    float sv[32];
    float mx = -1e30f;
#pragma unroll
    for (int jj = 0; jj < 32; ++jj) {
      const int col = jj * 16 + tc;
      size_t base = ((size_t)b * 64 + row) * 512 + col;
      float v = Sp[base] + Sp[base + 262144] + Sp[base + 524288] + Sp[base + 786432];
      sv[jj] = v;
      mx = fmaxf(mx, v);
    }
#pragma unroll
    for (int o = 1; o < 16; o <<= 1) mx = fmaxf(mx, __shfl_xor(mx, o, 64));
    float sum = 0.f;
#pragma unroll
    for (int jj = 0; jj < 32; ++jj) {
      float e = exp2fast(sv[jj] - mx);
      sv[jj] = e;
      sum += e;
    }
#pragma unroll
    for (int o = 1; o < 16; o <<= 1) sum += __shfl_xor(sum, o, 64);
    const float rs = 1.0f / sum;
#pragma unroll
    for (int jj = 0; jj < 32; ++jj)
      P[((size_t)b * 64 + row) * 512 + jj * 16 + tc] = f2bf(sv[jj] * rs);
  }
}

// ---------------- conv5 body (one stem): bid in [0,256) --------------------
__device__ __forceinline__ void conv5_body(char* ws, const float* b1p, int s, int bid)
{
  __shared__ float Hbuf[2][16][65];
  __shared__ float red[2][2];

  const int b = bid >> 5, pt = bid & 31;
  const int w = threadIdx.x >> 6, lane = threadIdx.x & 63;
  const int low4 = lane & 15, quad = lane >> 4;
  const int wsub = w & 1, half = w >> 1;

  const unsigned short* X = (const unsigned short*)(ws + (s ? O_XC : O_XS));
  const unsigned short* W1t = (const unsigned short*)(ws + O_W1T);
  unsigned short* Yt = (unsigned short*)(ws + O_YT);
  float* stats = (float*)(ws + O_STATS);

  const int p = pt * 32 + wsub * 16 + low4;
  const int y0 = p >> 5, x0 = p & 31;

  f4 acc[4];
#pragma unroll
  for (int m = 0; m < 4; ++m) acc[m] = (f4){0.f, 0.f, 0.f, 0.f};

  const int o0 = half ? 13 : 0, o1 = half ? 25 : 13;
  for (int off = o0; off < o1; ++off) {
    const int dy = off / 5 - 2, dx = off % 5 - 2;
    const int ys = y0 + dy, xs = x0 + dx;
    const bool valid = ((unsigned)ys < 32u) & ((unsigned)xs < 32u);
    const int psrc = valid ? (p + dy * 32 + dx) : p;
    const unsigned short* xp = X + ((size_t)(b * 1024 + psrc)) * 64;
    const unsigned short* wp = W1t + ((size_t)((s * 25 + off) * 64)) * 64;
#pragma unroll
    for (int ks = 0; ks < 2; ++ks) {
      short8 bv = *(const short8*)(xp + ks * 32 + quad * 8);
      if (!valid) bv = (short8)0;
#pragma unroll
      for (int m = 0; m < 4; ++m) {
        short8 av = *(const short8*)(wp + (m * 16 + low4) * 64 + ks * 32 + quad * 8);
        acc[m] = MFMA16(av, bv, acc[m]);
      }
    }
  }

  if (half) {
#pragma unroll
    for (int m = 0; m < 4; ++m)
#pragma unroll
      for (int r = 0; r < 4; ++r)
        Hbuf[wsub][low4][m * 16 + quad * 4 + r] = acc[m][r];
  }
  __syncthreads();
  if (!half) {
    float ls = 0.f, ls2 = 0.f;
#pragma unroll
    for (int m = 0; m < 4; ++m)
#pragma unroll
      for (int r = 0; r < 4; ++r) {
        const int co = m * 16 + quad * 4 + r;
        float y = acc[m][r] + Hbuf[wsub][low4][co] + b1p[co];
        Yt[((size_t)((s * 8 + b) * 1024 + p)) * 64 + co] = f2bf(y);
        ls += y; ls2 += y * y;
      }
#pragma unroll
    for (int o = 1; o < 64; o <<= 1) {
      ls += __shfl_xor(ls, o, 64);
      ls2 += __shfl_xor(ls2, o, 64);
    }
    if (lane == 0) { red[0][wsub] = ls; red[1][wsub] = ls2; }
  }
  __syncthreads();
  if (threadIdx.x == 0) {
    atomicAdd(&stats[(s * 8 + b) * 2 + 0], red[0][0] + red[0][1]);
    atomicAdd(&stats[(s * 8 + b) * 2 + 1], red[1][0] + red[1][1]);
  }
}

// ---------------- final body (one stem): bid in [0,256) --------------------
__device__ __forceinline__ void final_body(char* ws, const float* b2p,
                                           float* out, int s, int bid)
{
  const int b = bid >> 5, pt = bid & 31;
  const int w = threadIdx.x >> 6, lane = threadIdx.x & 63;
  const int low4 = lane & 15, quad = lane >> 4;
  const int p2 = pt * 32 + (w & 1) * 16 + low4;
  const int nh0 = (w >> 1) * 64;

  const unsigned short* Yt = (const unsigned short*)(ws + O_YT);
  const unsigned short* LNW = (const unsigned short*)(ws + O_LNW);
  const unsigned short* LNB = (const unsigned short*)(ws + O_LNB);
  const unsigned short* W2b = (const unsigned short*)(ws + O_W2B);
  const float* stats = (const float*)(ws + O_STATS);

  const float inv = 1.0f / 65536.0f;
  const float mu = stats[(s * 8 + b) * 2 + 0] * inv;
  const float ms = stats[(s * 8 + b) * 2 + 1] * inv;
  const float rsig = rsqrtf(ms - mu * mu + 1e-5f);

  f4 acc[4];
#pragma unroll
  for (int m = 0; m < 4; ++m) acc[m] = (f4){0.f, 0.f, 0.f, 0.f};

#pragma unroll
  for (int ks = 0; ks < 2; ++ks) {
    size_t yo = ((size_t)((s * 8 + b) * 1024 + p2)) * 64 + ks * 32 + quad * 8;
    size_t lo = ((size_t)(s * 1024 + p2)) * 64 + ks * 32 + quad * 8;
    short8 yv = *(const short8*)(Yt + yo);
    short8 lw8 = *(const short8*)(LNW + lo);
    short8 lb8 = *(const short8*)(LNB + lo);
    short8 zv;
#pragma unroll
    for (int j = 0; j < 8; ++j) {
      float z = (bf2f((unsigned short)yv[j]) - mu) * rsig * bf2f((unsigned short)lw8[j]) +
                bf2f((unsigned short)lb8[j]);
      zv[j] = (short)f2bf(fmaxf(z, 0.f));
    }
#pragma unroll
    for (int m = 0; m < 4; ++m) {
      short8 a = *(const short8*)(W2b + ((size_t)(s * 128 + nh0 + m * 16 + low4)) * 64 + ks * 32 + quad * 8);
      acc[m] = MFMA16(a, zv, acc[m]);
    }
  }
#pragma unroll
  for (int m = 0; m < 4; ++m)
#pragma unroll
    for (int r = 0; r < 4; ++r) {
      const int nh = nh0 + m * 16 + quad * 4 + r;
      out[((size_t)((s * 8 + b) * 128 + nh)) * 1024 + p2] = acc[m][r] + b2p[nh];
    }
}

// ============================================================================
// K4: conv5-spatial (0..255) ∪ chan_B (256..383)
// ============================================================================
__global__ __launch_bounds__(256) void k4_conv5s_chanB(
    const float* __restrict__ values, char* __restrict__ ws,
    const float* __restrict__ sb1)
{
  if (blockIdx.x < 256) { conv5_body(ws, sb1, 0, blockIdx.x); return; }

  // ---- chan_B: O = P @ V + residual (V gathered raw f32) ----
  const unsigned short* P = (const unsigned short*)(ws + O_PCH);
  const unsigned short* QT = (const unsigned short*)(ws + O_QT);
  unsigned short* Xc = (unsigned short*)(ws + O_XC);

  const int bid = blockIdx.x - 256;
  const int b = bid >> 4, pt = bid & 15;
  const int w = threadIdx.x >> 6, lane = threadIdx.x & 63;
  const int low4 = lane & 15, quad = lane >> 4;
  const int p = pt * 64 + w * 16 + low4;

  f4 acc[4];
#pragma unroll
  for (int m = 0; m < 4; ++m) acc[m] = (f4){0.f, 0.f, 0.f, 0.f};

  const float* vbase = values + (size_t)b * 524288 + p;
  for (int ks = 0; ks < 16; ++ks) {
    short8 vbv;
    const float* vp = vbase + (size_t)(ks * 32 + quad * 8) * 1024;
#pragma unroll
    for (int j = 0; j < 8; ++j) vbv[j] = (short)f2bf(vp[(size_t)j * 1024]);
#pragma unroll
    for (int m = 0; m < 4; ++m) {
      short8 a = *(const short8*)(P + ((size_t)(b * 64 + m * 16 + low4)) * 512 + ks * 32 + quad * 8);
      acc[m] = MFMA16(a, vbv, acc[m]);
    }
  }
#pragma unroll
  for (int m = 0; m < 4; ++m)
#pragma unroll
    for (int r = 0; r < 4; ++r) {
      const int c = m * 16 + quad * 4 + r;
      size_t o = ((size_t)(b * 1024 + p)) * 64 + c;
      Xc[o] = f2bf(acc[m][r] + bf2f(QT[o]));
    }
}

// ============================================================================
// K5: conv5-channel (0..255) ∪ final-spatial (256..511)
// ============================================================================
__global__ __launch_bounds__(256) void k5_conv5c_finS(
    char* __restrict__ ws, const float* __restrict__ cb1,
    const float* __restrict__ sb2, float* __restrict__ out)
{
  if (blockIdx.x < 256) { conv5_body(ws, cb1, 1, blockIdx.x); return; }
  final_body(ws, sb2, out, 0, blockIdx.x - 256);
}

// ============================================================================
// K6: final-channel (256 blocks)
// ============================================================================
__global__ __launch_bounds__(256) void k6_finC(
    char* __restrict__ ws, const float* __restrict__ cb2,
    float* __restrict__ out)
{
  final_body(ws, cb2, out, 1, blockIdx.x);
}

extern "C" void kernel_launch(void* const* d_in, const int* in_sizes, int n_in,
                              void* d_out, int out_size, void* d_ws, size_t ws_size,
                              hipStream_t stream)
{
  const float* q    = (const float*)d_in[0];
  const float* keys = (const float*)d_in[1];
  const float* vals = (const float*)d_in[2];
  const float* sw1  = (const float*)d_in[3];
  const float* sb1  = (const float*)d_in[4];
  const float* slnw = (const float*)d_in[5];
  const float* slnb = (const float*)d_in[6];
  const float* sw2  = (const float*)d_in[7];
  const float* sb2  = (const float*)d_in[8];
  const float* cw1  = (const float*)d_in[9];
  const float* cb1  = (const float*)d_in[10];
  const float* clnw = (const float*)d_in[11];
  const float* clnb = (const float*)d_in[12];
  const float* cw2  = (const float*)d_in[13];
  const float* cb2  = (const float*)d_in[14];
  char* ws = (char*)d_ws;

  (void)hipMemsetAsync(ws + O_STATS, 0, 256, stream);
  k1_prep<<<3104, 256, 0, stream>>>(q, keys, vals, sw1, slnw, slnb, sw2,
                                    cw1, clnw, clnb, cw2, ws);
  k2_spat_chanS<<<640, 256, 0, stream>>>(q, keys, ws);
  k3_fin_soft<<<544, 256, 0, stream>>>(ws);
  k4_conv5s_chanB<<<384, 256, 0, stream>>>(vals, ws, sb1);
  k5_conv5c_finS<<<512, 256, 0, stream>>>(ws, cb1, sb2, (float*)d_out);
  k6_finC<<<256, 256, 0, stream>>>(ws, cb2, (float*)d_out);
}

// Round 2
// 208.544 us; speedup vs baseline: 1.0089x; 1.0089x over previous
//
#include <hip/hip_runtime.h>

// ---------------------------------------------------------------------------
// DualAttention on MI355X.  B=8 L=8 C=64 W=32 (WH=1024, LWH=8192) NH=128 FS=5
// R9: revert k2 spatial to R7 inner loop (full 4-n S phase -> 2-ks PV, XOR-
//   swizzled Pl, 64KB LDS).  chan_S moved OUT of k2 into k1 as blocks 0..127
//   (it depends only on raw q/keys, not on k1's outputs) -> overlaps MFMA
//   work with k1's memory-bound transposes, and k2 becomes exactly 512
//   blocks = full 2-blocks/CU residency with no tail.  memset folded into k1.
// ---------------------------------------------------------------------------

#define LOG2E 1.44269504088896340736f

typedef __attribute__((ext_vector_type(8))) short short8;   // bf16 x8 frag
typedef __attribute__((ext_vector_type(4))) float f4;       // fp32 x4 frag

#define MFMA16(a, b, c) __builtin_amdgcn_mfma_f32_16x16x32_bf16(a, b, c, 0, 0, 0)

#define GLOAD_LDS16(gp, lp) __builtin_amdgcn_global_load_lds( \
    (const __attribute__((address_space(1))) void*)(gp), \
    (__attribute__((address_space(3))) void*)(lp), 16, 0, 0)

__device__ __forceinline__ unsigned short f2bf(float f) {   // RNE float->bf16
  union { float f; unsigned u; } v; v.f = f;
  unsigned r = v.u + 0x7FFFu + ((v.u >> 16) & 1u);
  return (unsigned short)(r >> 16);
}
__device__ __forceinline__ unsigned short f2bf_rz(float f) { // truncate (P only)
  union { float f; unsigned u; } v; v.f = f;
  return (unsigned short)(v.u >> 16);
}
__device__ __forceinline__ float bf2f(unsigned short h) {
  union { unsigned u; float f; } v; v.u = ((unsigned)h) << 16;
  return v.f;
}
__device__ __forceinline__ float exp2fast(float x) {
#if __has_builtin(__builtin_amdgcn_exp2f)
  return __builtin_amdgcn_exp2f(x);
#else
  return exp2f(x);
#endif
}

// ---------------- workspace layout (bytes), total ~45.0MB ------------------
#define O_STATS 0ul                      // [2][8][2] f32 (zeroed in k1)
#define O_W1T   256ul                    // [2][25][64][64] bf16
#define O_W2B   409856ul                 // [2][128][64] bf16
#define O_LNW   442624ul                 // [2][1024][64] bf16 (transposed lnw)
#define O_LNB   704768ul                 // [2][1024][64] bf16
#define O_QT    966912ul                 // [8][1024][64] bf16  q^T
#define O_KSP   2015488ul                // [8][8192][64] bf16  spatial K *LOG2E
#define O_VT    10404096ul               // [8][64][8192] bf16  spatial V^T
#define O_NUM   18792704ul               // [8][1024][16][64] bf16 spat num part
#define O_DEN   35569920ul               // [8][1024][16] f32      spat den part
#define O_SP    36094208ul               // [4][8][64][512] f32 chan S partials
#define O_PCH   40288512ul               // [8][64][512] bf16   chan P
#define O_XS    40812800ul               // [8][1024][64] bf16 stem in (spatial)
#define O_XC    41861376ul               // [8][1024][64] bf16 stem in (channel)
#define O_YT    42909952ul               // [2][8][1024][64] bf16 conv1 out

// ============================================================================
// K1: chan_S GEMM (blocks 0..127) ∪ tile/LN/weight prep (128..3231).
// chan_S first so its long MFMA blocks start immediately and overlap the
// memory-bound prep stream.  Block 0 also zeroes the stats accumulators.
// ============================================================================
__global__ __launch_bounds__(256) void k1_prep(
    const float* __restrict__ q, const float* __restrict__ keys,
    const float* __restrict__ values,
    const float* __restrict__ sw1, const float* __restrict__ slnw,
    const float* __restrict__ slnb, const float* __restrict__ sw2,
    const float* __restrict__ cw1, const float* __restrict__ clnw,
    const float* __restrict__ clnb, const float* __restrict__ cw2,
    char* __restrict__ ws)
{
  __shared__ __align__(16) unsigned char SM1[49152];   // chanS dbuf / prep T
  const int t = threadIdx.x;

  if (blockIdx.x < 128) {                // ================= chan_S ==========
    float* Sp = (float*)(ws + O_SP);
    const int bid = blockIdx.x;
    if (bid == 0 && t < 64) ((float*)(ws + O_STATS))[t] = 0.f;
    const int b = bid >> 4, colT = (bid >> 2) & 3, kt = bid & 3;
    const int w = t >> 6, lane = t & 63;
    const int low4 = lane & 15, quad = lane >> 4;
    const int dl = lane >> 1, dh = lane & 1;
    const int k00 = kt * 256;

    // buf layout (per buf, 24576B): K f32 tile at +0 (16KB), Q at +16384 (8KB)
    f4 acc[4][2];
#pragma unroll
    for (int m = 0; m < 4; ++m)
#pragma unroll
      for (int n = 0; n < 2; ++n) acc[m][n] = (f4){0.f, 0.f, 0.f, 0.f};

    auto stageAll = [&](int bo, int k0) {
#pragma unroll
      for (int gi = 0; gi < 4; ++gi) {           // K: groups w, w+4, w+8, w+12
        const int g = w + gi * 4;
        const int n = g >> 1, sub = g & 1;
        const int l = sub * 32 + dl;
        const float* gp = keys + (size_t)(b * 512 + colT * 128 + n * 16 + (l & 15)) * 1024
                          + k0 + (l >> 4) * 8 + dh * 4;
        GLOAD_LDS16(gp, SM1 + bo + (size_t)(n * 128 + sub * 64) * 16);
      }
#pragma unroll
      for (int gi = 0; gi < 2; ++gi) {           // Q: groups w, w+4
        const int g = w + gi * 4;
        const int m = g >> 1, sub = g & 1;
        const int l = sub * 32 + dl;
        const float* gp = q + (size_t)(b * 64 + m * 16 + (l & 15)) * 1024
                          + k0 + (l >> 4) * 8 + dh * 4;
        GLOAD_LDS16(gp, SM1 + bo + 16384 + (size_t)(m * 128 + sub * 64) * 16);
      }
    };

    stageAll(0, k00);
    for (int it = 0; it < 8; ++it) {
      const int bo = (it & 1) * 24576;
      const char* cb = (const char*)SM1 + bo;
      __syncthreads();
      if (it < 7) stageAll(bo ^ 24576, k00 + (it + 1) * 32);

      short8 ah[4], al[4];
#pragma unroll
      for (int m = 0; m < 4; ++m) {              // A-frags from LDS, *LOG2E, split
        const float* fp = (const float*)(cb + 16384 + (size_t)(m * 128 + lane * 2) * 16);
        float4 u0 = ((const float4*)fp)[0];
        float4 u1 = ((const float4*)fp)[1];
        float vv[8] = {u0.x, u0.y, u0.z, u0.w, u1.x, u1.y, u1.z, u1.w};
#pragma unroll
        for (int j = 0; j < 8; ++j) {
          float sv = vv[j] * LOG2E;
          unsigned short hi = f2bf(sv);
          ah[m][j] = (short)hi;
          al[m][j] = (short)f2bf(sv - bf2f(hi));
        }
      }
#pragma unroll
      for (int n2 = 0; n2 < 2; ++n2) {           // B-frags (this wave's 2 n-tiles)
        const int n = w * 2 + n2;
        const float* fp = (const float*)(cb + (size_t)(n * 128 + lane * 2) * 16);
        float4 u0 = ((const float4*)fp)[0];
        float4 u1 = ((const float4*)fp)[1];
        float vv[8] = {u0.x, u0.y, u0.z, u0.w, u1.x, u1.y, u1.z, u1.w};
        short8 bh, bl;
#pragma unroll
        for (int j = 0; j < 8; ++j) {
          unsigned short hi = f2bf(vv[j]);
          bh[j] = (short)hi;
          bl[j] = (short)f2bf(vv[j] - bf2f(hi));
        }
#pragma unroll
        for (int m = 0; m < 4; ++m) {
          acc[m][n2] = MFMA16(ah[m], bh, acc[m][n2]);
          acc[m][n2] = MFMA16(al[m], bh, acc[m][n2]);
          acc[m][n2] = MFMA16(ah[m], bl, acc[m][n2]);
        }
      }
    }

#pragma unroll
    for (int m = 0; m < 4; ++m)
#pragma unroll
      for (int n2 = 0; n2 < 2; ++n2)
#pragma unroll
        for (int r = 0; r < 4; ++r) {
          const int row = m * 16 + quad * 4 + r;
          const int col = colT * 128 + (w * 2 + n2) * 16 + low4;
          Sp[(((size_t)kt * 8 + b) * 64 + row) * 512 + col] = acc[m][n2][r];
        }
    return;
  }

  // ================= prep jobs =================
  float (*T)[65] = (float(*)[65])SM1;
  const int job = blockIdx.x - 128;

  if (job < 2240) {                      // ---- tile jobs ----
    int kind, mat = 0, sel = 0;
    if (job < 1024)      { kind = 0; mat = job >> 4; }
    else if (job < 2048) { kind = 1; mat = (job - 1024) >> 4; }
    else if (job < 2176) { kind = 2; mat = (job - 2048) >> 4; }
    else                 { kind = 3; sel = (job - 2176) >> 4; }
    const int pt = job & 15, p0 = pt * 64;
    const float* src =
        kind == 0 ? keys : kind == 1 ? values : kind == 2 ? q
        : (sel == 0 ? slnw : sel == 1 ? slnb : sel == 2 ? clnw : clnb);
    src += (size_t)mat * 65536;

    const int r0 = t >> 4, c4 = (t & 15) * 4;
    if (kind == 1) {                     // identity only: V^T[b][c][l*1024+p]
      unsigned short* VTp = (unsigned short*)(ws + O_VT);
      const int b = mat >> 3, l = mat & 7;
#pragma unroll
      for (int pass = 0; pass < 4; ++pass) {
        const int r = pass * 16 + r0;
        float4 v = *(const float4*)(src + (size_t)r * 1024 + p0 + c4);
        ushort4 o;
        o.x = f2bf(v.x); o.y = f2bf(v.y); o.z = f2bf(v.z); o.w = f2bf(v.w);
        *(ushort4*)(VTp + ((size_t)b * 64 + r) * 8192 + l * 1024 + p0 + c4) = o;
      }
      return;
    }
#pragma unroll
    for (int pass = 0; pass < 4; ++pass) {
      const int r = pass * 16 + r0;
      float4 v = *(const float4*)(src + (size_t)r * 1024 + p0 + c4);
      T[r][c4] = v.x; T[r][c4 + 1] = v.y; T[r][c4 + 2] = v.z; T[r][c4 + 3] = v.w;
    }
    __syncthreads();
#pragma unroll
    for (int pass = 0; pass < 2; ++pass) {
      const int p = pass * 32 + (t >> 3), cs = (t & 7) * 8;
      short8 o;
      if (kind == 0) {                   // Ksp[b][l*1024+p][c] * LOG2E
#pragma unroll
        for (int j = 0; j < 8; ++j) o[j] = (short)f2bf(T[cs + j][p] * LOG2E);
        const int b = mat >> 3, l = mat & 7;
        *(short8*)((unsigned short*)(ws + O_KSP) +
                   ((size_t)b * 8192 + l * 1024 + p0 + p) * 64 + cs) = o;
      } else if (kind == 2) {            // Qt[b][p][c]
#pragma unroll
        for (int j = 0; j < 8; ++j) o[j] = (short)f2bf(T[cs + j][p]);
        *(short8*)((unsigned short*)(ws + O_QT) +
                   ((size_t)mat * 1024 + p0 + p) * 64 + cs) = o;
      } else {                           // LN param^T [s][p][c]
#pragma unroll
        for (int j = 0; j < 8; ++j) o[j] = (short)f2bf(T[cs + j][p]);
        unsigned long off = (sel & 1) ? O_LNB : O_LNW;
        *(short8*)((unsigned short*)(ws + off) +
                   ((size_t)(sel >> 1) * 1024 + p0 + p) * 64 + cs) = o;
      }
    }
    return;
  }

  // ---- weights ----
  {
    unsigned i = (job - 2240) * 256u + t;
    if (i < 204800u) {                   // W1t[s][off][co][ci] <- w1[co][ci][off]
      unsigned ci = i & 63u, co = (i >> 6) & 63u, tt = i >> 12;
      unsigned off = tt % 25u, st = tt / 25u;
      const float* w = st ? cw1 : sw1;
      ((unsigned short*)(ws + O_W1T))[i] = f2bf(w[(co * 64u + ci) * 25u + off]);
      return;
    }
    i -= 204800u;
    if (i < 16384u) {                    // W2b[s][nh][c]
      unsigned c = i & 63u, nh = (i >> 6) & 127u, st = i >> 13;
      const float* w = st ? cw2 : sw2;
      ((unsigned short*)(ws + O_W2B))[i] = f2bf(w[nh * 64u + c]);
    }
  }
}

// ============================================================================
// K2: spatial attention, 512 blocks (exact full residency at 2 blocks/CU).
// R7 inner loop: M=4, lane-linear frag staging, dbuf, den-MFMA, kv-split 16,
// full 4-n S phase into XOR-swizzled Pl then 2-ks PV phase.
// ============================================================================
__global__ __launch_bounds__(256) void k2_spat(char* __restrict__ ws)
{
  __shared__ __align__(16) unsigned char SM[65536];

  unsigned short (*Kt)[4096] = (unsigned short(*)[4096])(SM);
  unsigned short (*Vt)[4096] = (unsigned short(*)[4096])(SM + 16384);
  unsigned short (*Pl)[4096] = (unsigned short(*)[4096])(SM + 32768);

  const unsigned short* QT = (const unsigned short*)(ws + O_QT);
  const unsigned short* KSP = (const unsigned short*)(ws + O_KSP);
  const unsigned short* VTg = (const unsigned short*)(ws + O_VT);
  unsigned short* NUM = (unsigned short*)(ws + O_NUM);
  float* DEN = (float*)(ws + O_DEN);

  const int b = blockIdx.x >> 6;
  const int qt = (blockIdx.x >> 4) & 3;
  const int s = blockIdx.x & 15;
  const int t = threadIdx.x;
  const int w = t >> 6, lane = t & 63;
  const int low4 = lane & 15, quad = lane >> 4;

  const unsigned short* KSPb = KSP + (size_t)b * 8192 * 64;
  const unsigned short* VTb = VTg + (size_t)b * 64 * 8192;
  const int qbase = qt * 256 + w * 64;
  const int kvbase = s * 512;

  int cn[2], cks[2], cqd[2], cl4[2];
#pragma unroll
  for (int pass = 0; pass < 2; ++pass) {
    const int c = pass * 256 + t;
    cn[pass] = c >> 7; cks[pass] = (c >> 6) & 1;
    cqd[pass] = (c >> 4) & 3; cl4[pass] = c & 15;
  }

  short8 qa[4][2];
#pragma unroll
  for (int mi = 0; mi < 4; ++mi)
#pragma unroll
    for (int ks = 0; ks < 2; ++ks)
      qa[mi][ks] = *(const short8*)(QT +
          ((size_t)(b * 1024 + qbase + mi * 16 + low4)) * 64 + ks * 32 + quad * 8);

  short8 vones;
#pragma unroll
  for (int j = 0; j < 8; ++j) vones[j] = (short)0x3F80;

  f4 accO[4][4], accD[4];
#pragma unroll
  for (int m = 0; m < 4; ++m) {
    accD[m] = (f4){0.f, 0.f, 0.f, 0.f};
#pragma unroll
    for (int n = 0; n < 4; ++n) accO[m][n] = (f4){0.f, 0.f, 0.f, 0.f};
  }

#pragma unroll
  for (int pass = 0; pass < 2; ++pass) {
    GLOAD_LDS16(KSPb + ((size_t)(kvbase + cn[pass] * 16 + cl4[pass])) * 64 +
                    cks[pass] * 32 + cqd[pass] * 8,
                &Kt[0][(pass * 256 + w * 64) * 8]);
    GLOAD_LDS16(VTb + ((size_t)(cn[pass] * 16 + cl4[pass])) * 8192 + kvbase +
                    cks[pass] * 32 + cqd[pass] * 8,
                &Vt[0][(pass * 256 + w * 64) * 8]);
  }

  const int pswz = ((low4 >> 2) & 3) << 1;
  for (int it = 0; it < 8; ++it) {
    const int d = it & 1;
    __syncthreads();
    if (it < 7) {
      const int kv1 = kvbase + (it + 1) * 64;
#pragma unroll
      for (int pass = 0; pass < 2; ++pass) {
        GLOAD_LDS16(KSPb + ((size_t)(kv1 + cn[pass] * 16 + cl4[pass])) * 64 +
                        cks[pass] * 32 + cqd[pass] * 8,
                    &Kt[d ^ 1][(pass * 256 + w * 64) * 8]);
        GLOAD_LDS16(VTb + ((size_t)(cn[pass] * 16 + cl4[pass])) * 8192 + kv1 +
                        cks[pass] * 32 + cqd[pass] * 8,
                    &Vt[d ^ 1][(pass * 256 + w * 64) * 8]);
      }
    }
#pragma unroll
    for (int n = 0; n < 4; ++n) {
      f4 sS[4];
#pragma unroll
      for (int mi = 0; mi < 4; ++mi) sS[mi] = (f4){0.f, 0.f, 0.f, 0.f};
#pragma unroll
      for (int ks = 0; ks < 2; ++ks) {
        short8 kb = *(const short8*)&Kt[d][((n * 2 + ks) * 64 + lane) * 8];
#pragma unroll
        for (int mi = 0; mi < 4; ++mi) sS[mi] = MFMA16(qa[mi][ks], kb, sS[mi]);
      }
      const int cpr = (((n * 2 + (low4 >> 3)) ^ (quad << 1)) << 3) + (low4 & 7);
#pragma unroll
      for (int mi = 0; mi < 4; ++mi) {
        unsigned short* pw = &Pl[w][(mi * 16 + quad * 4) * 64 + cpr];
#pragma unroll
        for (int r = 0; r < 4; ++r)
          pw[r * 64] = f2bf_rz(exp2fast(sS[mi][r]));
      }
    }
#pragma unroll
    for (int ks = 0; ks < 2; ++ks) {
      short8 vb[4];
#pragma unroll
      for (int n2 = 0; n2 < 4; ++n2)
        vb[n2] = *(const short8*)&Vt[d][((n2 * 2 + ks) * 64 + lane) * 8];
      const int cr = (((ks * 4 + quad) ^ pswz) << 3);
#pragma unroll
      for (int m = 0; m < 4; ++m) {
        short8 pa = *(const short8*)&Pl[w][(m * 16 + low4) * 64 + cr];
        accD[m] = MFMA16(pa, vones, accD[m]);
#pragma unroll
        for (int n2 = 0; n2 < 4; ++n2) accO[m][n2] = MFMA16(pa, vb[n2], accO[m][n2]);
      }
    }
  }

#pragma unroll
  for (int m = 0; m < 4; ++m)
#pragma unroll
    for (int r = 0; r < 4; ++r) {
      const int row = qbase + m * 16 + quad * 4 + r;
      const size_t base = ((size_t)(b * 1024 + row) * 16 + s);
#pragma unroll
      for (int n2 = 0; n2 < 4; ++n2)
        NUM[base * 64 + n2 * 16 + low4] = f2bf(accO[m][n2][r]);
      if (low4 == 0) DEN[base] = accD[m][r];
    }
}

// ============================================================================
// K3: spat_fin (blocks 0..511) ∪ chan_soft (512..543)
// ============================================================================
__global__ __launch_bounds__(256) void k3_fin_soft(char* __restrict__ ws)
{
  if (blockIdx.x < 512) {                // ---- spat_fin: 16 bf16 partials ----
    const unsigned short* NUM = (const unsigned short*)(ws + O_NUM);
    const float* DEN = (const float*)(ws + O_DEN);
    const unsigned short* QT = (const unsigned short*)(ws + O_QT);
    unsigned short* Xs = (unsigned short*)(ws + O_XS);

    const unsigned i = blockIdx.x * 256u + threadIdx.x;   // 131072
    const int c0 = (i & 15) * 4;
    const unsigned row = i >> 4;                          // [0, 8192)

    float dtot = 0.f;
#pragma unroll
    for (int sq = 0; sq < 4; ++sq) {
      float4 dv = *(const float4*)(DEN + (size_t)row * 16 + sq * 4);
      dtot += dv.x + dv.y + dv.z + dv.w;
    }
    float n4[4] = {0.f, 0.f, 0.f, 0.f};
#pragma unroll
    for (int s = 0; s < 16; ++s) {
      ushort4 pv = *(const ushort4*)(NUM + ((size_t)row * 16 + s) * 64 + c0);
      n4[0] += bf2f(pv.x); n4[1] += bf2f(pv.y);
      n4[2] += bf2f(pv.z); n4[3] += bf2f(pv.w);
    }
    const float rd = 1.0f / dtot;
    size_t ob = (size_t)row * 64 + c0;
    ushort4 qv = *(const ushort4*)(QT + ob);
    ushort4 o4;
    o4.x = f2bf(n4[0] * rd + bf2f(qv.x));
    o4.y = f2bf(n4[1] * rd + bf2f(qv.y));
    o4.z = f2bf(n4[2] * rd + bf2f(qv.z));
    o4.w = f2bf(n4[3] * rd + bf2f(qv.w));
    *(ushort4*)(Xs + ob) = o4;
    return;
  }

  // ---- chan_soft: sum 4 partials, max-sub, exp2, normalize -> P ----
  {
    const float* Sp = (const float*)(ws + O_SP);
    unsigned short* P = (unsigned short*)(ws + O_PCH);
    const int bid = blockIdx.x - 512;
    const int b = bid >> 2, rt = bid & 3;
    const int row = rt * 16 + (threadIdx.x >> 4), tc = threadIdx.x & 15;

    float sv[32];
    float mx = -1e30f;
#pragma unroll
    for (int jj = 0; jj < 32; ++jj) {
      const int col = jj * 16 + tc;
      size_t base = ((size_t)b * 64 + row) * 512 + col;
      float v = Sp[base] + Sp[base + 262144] + Sp[base + 524288] + Sp[base + 786432];
      sv[jj] = v;
      mx = fmaxf(mx, v);
    }
#pragma unroll
    for (int o = 1; o < 16; o <<= 1) mx = fmaxf(mx, __shfl_xor(mx, o, 64));
    float sum = 0.f;
#pragma unroll
    for (int jj = 0; jj < 32; ++jj) {
      float e = exp2fast(sv[jj] - mx);
      sv[jj] = e;
      sum += e;
    }
#pragma unroll
    for (int o = 1; o < 16; o <<= 1) sum += __shfl_xor(sum, o, 64);
    const float rs = 1.0f / sum;
#pragma unroll
    for (int jj = 0; jj < 32; ++jj)
      P[((size_t)b * 64 + row) * 512 + jj * 16 + tc] = f2bf(sv[jj] * rs);
  }
}

// ---------------- conv5 body (one stem): bid in [0,256) --------------------
__device__ __forceinline__ void conv5_body(char* ws, const float* b1p, int s, int bid)
{
  __shared__ float Hbuf[2][16][65];
  __shared__ float red[2][2];

  const int b = bid >> 5, pt = bid & 31;
  const int w = threadIdx.x >> 6, lane = threadIdx.x & 63;
  const int low4 = lane & 15, quad = lane >> 4;
  const int wsub = w & 1, half = w >> 1;

  const unsigned short* X = (const unsigned short*)(ws + (s ? O_XC : O_XS));
  const unsigned short* W1t = (const unsigned short*)(ws + O_W1T);
  unsigned short* Yt = (unsigned short*)(ws + O_YT);
  float* stats = (float*)(ws + O_STATS);

  const int p = pt * 32 + wsub * 16 + low4;
  const int y0 = p >> 5, x0 = p & 31;

  f4 acc[4];
#pragma unroll
  for (int m = 0; m < 4; ++m) acc[m] = (f4){0.f, 0.f, 0.f, 0.f};

  const int o0 = half ? 13 : 0, o1 = half ? 25 : 13;
  for (int off = o0; off < o1; ++off) {
    const int dy = off / 5 - 2, dx = off % 5 - 2;
    const int ys = y0 + dy, xs = x0 + dx;
    const bool valid = ((unsigned)ys < 32u) & ((unsigned)xs < 32u);
    const int psrc = valid ? (p + dy * 32 + dx) : p;
    const unsigned short* xp = X + ((size_t)(b * 1024 + psrc)) * 64;
    const unsigned short* wp = W1t + ((size_t)((s * 25 + off) * 64)) * 64;
#pragma unroll
    for (int ks = 0; ks < 2; ++ks) {
      short8 bv = *(const short8*)(xp + ks * 32 + quad * 8);
      if (!valid) bv = (short8)0;
#pragma unroll
      for (int m = 0; m < 4; ++m) {
        short8 av = *(const short8*)(wp + (m * 16 + low4) * 64 + ks * 32 + quad * 8);
        acc[m] = MFMA16(av, bv, acc[m]);
      }
    }
  }

  if (half) {
#pragma unroll
    for (int m = 0; m < 4; ++m)
#pragma unroll
      for (int r = 0; r < 4; ++r)
        Hbuf[wsub][low4][m * 16 + quad * 4 + r] = acc[m][r];
  }
  __syncthreads();
  if (!half) {
    float ls = 0.f, ls2 = 0.f;
#pragma unroll
    for (int m = 0; m < 4; ++m)
#pragma unroll
      for (int r = 0; r < 4; ++r) {
        const int co = m * 16 + quad * 4 + r;
        float y = acc[m][r] + Hbuf[wsub][low4][co] + b1p[co];
        Yt[((size_t)((s * 8 + b) * 1024 + p)) * 64 + co] = f2bf(y);
        ls += y; ls2 += y * y;
      }
#pragma unroll
    for (int o = 1; o < 64; o <<= 1) {
      ls += __shfl_xor(ls, o, 64);
      ls2 += __shfl_xor(ls2, o, 64);
    }
    if (lane == 0) { red[0][wsub] = ls; red[1][wsub] = ls2; }
  }
  __syncthreads();
  if (threadIdx.x == 0) {
    atomicAdd(&stats[(s * 8 + b) * 2 + 0], red[0][0] + red[0][1]);
    atomicAdd(&stats[(s * 8 + b) * 2 + 1], red[1][0] + red[1][1]);
  }
}

// ---------------- final body (one stem): bid in [0,256) --------------------
__device__ __forceinline__ void final_body(char* ws, const float* b2p,
                                           float* out, int s, int bid)
{
  const int b = bid >> 5, pt = bid & 31;
  const int w = threadIdx.x >> 6, lane = threadIdx.x & 63;
  const int low4 = lane & 15, quad = lane >> 4;
  const int p2 = pt * 32 + (w & 1) * 16 + low4;
  const int nh0 = (w >> 1) * 64;

  const unsigned short* Yt = (const unsigned short*)(ws + O_YT);
  const unsigned short* LNW = (const unsigned short*)(ws + O_LNW);
  const unsigned short* LNB = (const unsigned short*)(ws + O_LNB);
  const unsigned short* W2b = (const unsigned short*)(ws + O_W2B);
  const float* stats = (const float*)(ws + O_STATS);

  const float inv = 1.0f / 65536.0f;
  const float mu = stats[(s * 8 + b) * 2 + 0] * inv;
  const float ms = stats[(s * 8 + b) * 2 + 1] * inv;
  const float rsig = rsqrtf(ms - mu * mu + 1e-5f);

  f4 acc[4];
#pragma unroll
  for (int m = 0; m < 4; ++m) acc[m] = (f4){0.f, 0.f, 0.f, 0.f};

#pragma unroll
  for (int ks = 0; ks < 2; ++ks) {
    size_t yo = ((size_t)((s * 8 + b) * 1024 + p2)) * 64 + ks * 32 + quad * 8;
    size_t lo = ((size_t)(s * 1024 + p2)) * 64 + ks * 32 + quad * 8;
    short8 yv = *(const short8*)(Yt + yo);
    short8 lw8 = *(const short8*)(LNW + lo);
    short8 lb8 = *(const short8*)(LNB + lo);
    short8 zv;
#pragma unroll
    for (int j = 0; j < 8; ++j) {
      float z = (bf2f((unsigned short)yv[j]) - mu) * rsig * bf2f((unsigned short)lw8[j]) +
                bf2f((unsigned short)lb8[j]);
      zv[j] = (short)f2bf(fmaxf(z, 0.f));
    }
#pragma unroll
    for (int m = 0; m < 4; ++m) {
      short8 a = *(const short8*)(W2b + ((size_t)(s * 128 + nh0 + m * 16 + low4)) * 64 + ks * 32 + quad * 8);
      acc[m] = MFMA16(a, zv, acc[m]);
    }
  }
#pragma unroll
  for (int m = 0; m < 4; ++m)
#pragma unroll
    for (int r = 0; r < 4; ++r) {
      const int nh = nh0 + m * 16 + quad * 4 + r;
      out[((size_t)((s * 8 + b) * 128 + nh)) * 1024 + p2] = acc[m][r] + b2p[nh];
    }
}

// ============================================================================
// K4: conv5-spatial (0..255) ∪ chan_B (256..383)
// ============================================================================
__global__ __launch_bounds__(256) void k4_conv5s_chanB(
    const float* __restrict__ values, char* __restrict__ ws,
    const float* __restrict__ sb1)
{
  if (blockIdx.x < 256) { conv5_body(ws, sb1, 0, blockIdx.x); return; }

  // ---- chan_B: O = P @ V + residual (V gathered raw f32) ----
  const unsigned short* P = (const unsigned short*)(ws + O_PCH);
  const unsigned short* QT = (const unsigned short*)(ws + O_QT);
  unsigned short* Xc = (unsigned short*)(ws + O_XC);

  const int bid = blockIdx.x - 256;
  const int b = bid >> 4, pt = bid & 15;
  const int w = threadIdx.x >> 6, lane = threadIdx.x & 63;
  const int low4 = lane & 15, quad = lane >> 4;
  const int p = pt * 64 + w * 16 + low4;

  f4 acc[4];
#pragma unroll
  for (int m = 0; m < 4; ++m) acc[m] = (f4){0.f, 0.f, 0.f, 0.f};

  const float* vbase = values + (size_t)b * 524288 + p;
  for (int ks = 0; ks < 16; ++ks) {
    short8 vbv;
    const float* vp = vbase + (size_t)(ks * 32 + quad * 8) * 1024;
#pragma unroll
    for (int j = 0; j < 8; ++j) vbv[j] = (short)f2bf(vp[(size_t)j * 1024]);
#pragma unroll
    for (int m = 0; m < 4; ++m) {
      short8 a = *(const short8*)(P + ((size_t)(b * 64 + m * 16 + low4)) * 512 + ks * 32 + quad * 8);
      acc[m] = MFMA16(a, vbv, acc[m]);
    }
  }
#pragma unroll
  for (int m = 0; m < 4; ++m)
#pragma unroll
    for (int r = 0; r < 4; ++r) {
      const int c = m * 16 + quad * 4 + r;
      size_t o = ((size_t)(b * 1024 + p)) * 64 + c;
      Xc[o] = f2bf(acc[m][r] + bf2f(QT[o]));
    }
}

// ============================================================================
// K5: conv5-channel (0..255) ∪ final-spatial (256..511)
// ============================================================================
__global__ __launch_bounds__(256) void k5_conv5c_finS(
    char* __restrict__ ws, const float* __restrict__ cb1,
    const float* __restrict__ sb2, float* __restrict__ out)
{
  if (blockIdx.x < 256) { conv5_body(ws, cb1, 1, blockIdx.x); return; }
  final_body(ws, sb2, out, 0, blockIdx.x - 256);
}

// ============================================================================
// K6: final-channel (256 blocks)
// ============================================================================
__global__ __launch_bounds__(256) void k6_finC(
    char* __restrict__ ws, const float* __restrict__ cb2,
    float* __restrict__ out)
{
  final_body(ws, cb2, out, 1, blockIdx.x);
}

extern "C" void kernel_launch(void* const* d_in, const int* in_sizes, int n_in,
                              void* d_out, int out_size, void* d_ws, size_t ws_size,
                              hipStream_t stream)
{
  const float* q    = (const float*)d_in[0];
  const float* keys = (const float*)d_in[1];
  const float* vals = (const float*)d_in[2];
  const float* sw1  = (const float*)d_in[3];
  const float* sb1  = (const float*)d_in[4];
  const float* slnw = (const float*)d_in[5];
  const float* slnb = (const float*)d_in[6];
  const float* sw2  = (const float*)d_in[7];
  const float* sb2  = (const float*)d_in[8];
  const float* cw1  = (const float*)d_in[9];
  const float* cb1  = (const float*)d_in[10];
  const float* clnw = (const float*)d_in[11];
  const float* clnb = (const float*)d_in[12];
  const float* cw2  = (const float*)d_in[13];
  const float* cb2  = (const float*)d_in[14];
  char* ws = (char*)d_ws;

  k1_prep<<<3232, 256, 0, stream>>>(q, keys, vals, sw1, slnw, slnb, sw2,
                                    cw1, clnw, clnb, cw2, ws);
  k2_spat<<<512, 256, 0, stream>>>(ws);
  k3_fin_soft<<<544, 256, 0, stream>>>(ws);
  k4_conv5s_chanB<<<384, 256, 0, stream>>>(vals, ws, sb1);
  k5_conv5c_finS<<<512, 256, 0, stream>>>(ws, cb1, sb2, (float*)d_out);
  k6_finC<<<256, 256, 0, stream>>>(ws, cb2, (float*)d_out);
}

// Round 3
// 205.265 us; speedup vs baseline: 1.0250x; 1.0160x over previous
//
#include <hip/hip_runtime.h>

// ---------------------------------------------------------------------------
// DualAttention on MI355X.  B=8 L=8 C=64 W=32 (WH=1024, LWH=8192) NH=128 FS=5
// R10: 5-kernel repack (no arithmetic changes vs R9).  DAG-tightened:
//   k1 = chanS GEMM (128) ∪ prep (3104)           [unchanged]
//   k2 = chan_soft (32, only needs k1) ∪ spat_attn (512)
//   k3 = chan_B (128, needs chan_soft) ∪ spat_fin (512)
//   k4 = conv5-spatial (256) ∪ conv5-channel (256)   -- perfect 2/CU
//   k5 = final-spatial (256) ∪ final-channel (256)   -- absorbs old k6
// Removes one launch, fixes k6's half-idle 256-block dispatch and k4's
// 1.5-generation 384-block dispatch.
// ---------------------------------------------------------------------------

#define LOG2E 1.44269504088896340736f

typedef __attribute__((ext_vector_type(8))) short short8;   // bf16 x8 frag
typedef __attribute__((ext_vector_type(4))) float f4;       // fp32 x4 frag

#define MFMA16(a, b, c) __builtin_amdgcn_mfma_f32_16x16x32_bf16(a, b, c, 0, 0, 0)

#define GLOAD_LDS16(gp, lp) __builtin_amdgcn_global_load_lds( \
    (const __attribute__((address_space(1))) void*)(gp), \
    (__attribute__((address_space(3))) void*)(lp), 16, 0, 0)

__device__ __forceinline__ unsigned short f2bf(float f) {   // RNE float->bf16
  union { float f; unsigned u; } v; v.f = f;
  unsigned r = v.u + 0x7FFFu + ((v.u >> 16) & 1u);
  return (unsigned short)(r >> 16);
}
__device__ __forceinline__ unsigned short f2bf_rz(float f) { // truncate (P only)
  union { float f; unsigned u; } v; v.f = f;
  return (unsigned short)(v.u >> 16);
}
__device__ __forceinline__ float bf2f(unsigned short h) {
  union { unsigned u; float f; } v; v.u = ((unsigned)h) << 16;
  return v.f;
}
__device__ __forceinline__ float exp2fast(float x) {
#if __has_builtin(__builtin_amdgcn_exp2f)
  return __builtin_amdgcn_exp2f(x);
#else
  return exp2f(x);
#endif
}

// ---------------- workspace layout (bytes), total ~45.0MB ------------------
#define O_STATS 0ul                      // [2][8][2] f32 (zeroed in k1)
#define O_W1T   256ul                    // [2][25][64][64] bf16
#define O_W2B   409856ul                 // [2][128][64] bf16
#define O_LNW   442624ul                 // [2][1024][64] bf16 (transposed lnw)
#define O_LNB   704768ul                 // [2][1024][64] bf16
#define O_QT    966912ul                 // [8][1024][64] bf16  q^T
#define O_KSP   2015488ul                // [8][8192][64] bf16  spatial K *LOG2E
#define O_VT    10404096ul               // [8][64][8192] bf16  spatial V^T
#define O_NUM   18792704ul               // [8][1024][16][64] bf16 spat num part
#define O_DEN   35569920ul               // [8][1024][16] f32      spat den part
#define O_SP    36094208ul               // [4][8][64][512] f32 chan S partials
#define O_PCH   40288512ul               // [8][64][512] bf16   chan P
#define O_XS    40812800ul               // [8][1024][64] bf16 stem in (spatial)
#define O_XC    41861376ul               // [8][1024][64] bf16 stem in (channel)
#define O_YT    42909952ul               // [2][8][1024][64] bf16 conv1 out

// ============================================================================
// K1: chan_S GEMM (blocks 0..127) ∪ tile/LN/weight prep (128..3231).
// ============================================================================
__global__ __launch_bounds__(256) void k1_prep(
    const float* __restrict__ q, const float* __restrict__ keys,
    const float* __restrict__ values,
    const float* __restrict__ sw1, const float* __restrict__ slnw,
    const float* __restrict__ slnb, const float* __restrict__ sw2,
    const float* __restrict__ cw1, const float* __restrict__ clnw,
    const float* __restrict__ clnb, const float* __restrict__ cw2,
    char* __restrict__ ws)
{
  __shared__ __align__(16) unsigned char SM1[49152];   // chanS dbuf / prep T
  const int t = threadIdx.x;

  if (blockIdx.x < 128) {                // ================= chan_S ==========
    float* Sp = (float*)(ws + O_SP);
    const int bid = blockIdx.x;
    if (bid == 0 && t < 64) ((float*)(ws + O_STATS))[t] = 0.f;
    const int b = bid >> 4, colT = (bid >> 2) & 3, kt = bid & 3;
    const int w = t >> 6, lane = t & 63;
    const int low4 = lane & 15, quad = lane >> 4;
    const int dl = lane >> 1, dh = lane & 1;
    const int k00 = kt * 256;

    // buf layout (per buf, 24576B): K f32 tile at +0 (16KB), Q at +16384 (8KB)
    f4 acc[4][2];
#pragma unroll
    for (int m = 0; m < 4; ++m)
#pragma unroll
      for (int n = 0; n < 2; ++n) acc[m][n] = (f4){0.f, 0.f, 0.f, 0.f};

    auto stageAll = [&](int bo, int k0) {
#pragma unroll
      for (int gi = 0; gi < 4; ++gi) {           // K: groups w, w+4, w+8, w+12
        const int g = w + gi * 4;
        const int n = g >> 1, sub = g & 1;
        const int l = sub * 32 + dl;
        const float* gp = keys + (size_t)(b * 512 + colT * 128 + n * 16 + (l & 15)) * 1024
                          + k0 + (l >> 4) * 8 + dh * 4;
        GLOAD_LDS16(gp, SM1 + bo + (size_t)(n * 128 + sub * 64) * 16);
      }
#pragma unroll
      for (int gi = 0; gi < 2; ++gi) {           // Q: groups w, w+4
        const int g = w + gi * 4;
        const int m = g >> 1, sub = g & 1;
        const int l = sub * 32 + dl;
        const float* gp = q + (size_t)(b * 64 + m * 16 + (l & 15)) * 1024
                          + k0 + (l >> 4) * 8 + dh * 4;
        GLOAD_LDS16(gp, SM1 + bo + 16384 + (size_t)(m * 128 + sub * 64) * 16);
      }
    };

    stageAll(0, k00);
    for (int it = 0; it < 8; ++it) {
      const int bo = (it & 1) * 24576;
      const char* cb = (const char*)SM1 + bo;
      __syncthreads();
      if (it < 7) stageAll(bo ^ 24576, k00 + (it + 1) * 32);

      short8 ah[4], al[4];
#pragma unroll
      for (int m = 0; m < 4; ++m) {              // A-frags from LDS, *LOG2E, split
        const float* fp = (const float*)(cb + 16384 + (size_t)(m * 128 + lane * 2) * 16);
        float4 u0 = ((const float4*)fp)[0];
        float4 u1 = ((const float4*)fp)[1];
        float vv[8] = {u0.x, u0.y, u0.z, u0.w, u1.x, u1.y, u1.z, u1.w};
#pragma unroll
        for (int j = 0; j < 8; ++j) {
          float sv = vv[j] * LOG2E;
          unsigned short hi = f2bf(sv);
          ah[m][j] = (short)hi;
          al[m][j] = (short)f2bf(sv - bf2f(hi));
        }
      }
#pragma unroll
      for (int n2 = 0; n2 < 2; ++n2) {           // B-frags (this wave's 2 n-tiles)
        const int n = w * 2 + n2;
        const float* fp = (const float*)(cb + (size_t)(n * 128 + lane * 2) * 16);
        float4 u0 = ((const float4*)fp)[0];
        float4 u1 = ((const float4*)fp)[1];
        float vv[8] = {u0.x, u0.y, u0.z, u0.w, u1.x, u1.y, u1.z, u1.w};
        short8 bh, bl;
#pragma unroll
        for (int j = 0; j < 8; ++j) {
          unsigned short hi = f2bf(vv[j]);
          bh[j] = (short)hi;
          bl[j] = (short)f2bf(vv[j] - bf2f(hi));
        }
#pragma unroll
        for (int m = 0; m < 4; ++m) {
          acc[m][n2] = MFMA16(ah[m], bh, acc[m][n2]);
          acc[m][n2] = MFMA16(al[m], bh, acc[m][n2]);
          acc[m][n2] = MFMA16(ah[m], bl, acc[m][n2]);
        }
      }
    }

#pragma unroll
    for (int m = 0; m < 4; ++m)
#pragma unroll
      for (int n2 = 0; n2 < 2; ++n2)
#pragma unroll
        for (int r = 0; r < 4; ++r) {
          const int row = m * 16 + quad * 4 + r;
          const int col = colT * 128 + (w * 2 + n2) * 16 + low4;
          Sp[(((size_t)kt * 8 + b) * 64 + row) * 512 + col] = acc[m][n2][r];
        }
    return;
  }

  // ================= prep jobs =================
  float (*T)[65] = (float(*)[65])SM1;
  const int job = blockIdx.x - 128;

  if (job < 2240) {                      // ---- tile jobs ----
    int kind, mat = 0, sel = 0;
    if (job < 1024)      { kind = 0; mat = job >> 4; }
    else if (job < 2048) { kind = 1; mat = (job - 1024) >> 4; }
    else if (job < 2176) { kind = 2; mat = (job - 2048) >> 4; }
    else                 { kind = 3; sel = (job - 2176) >> 4; }
    const int pt = job & 15, p0 = pt * 64;
    const float* src =
        kind == 0 ? keys : kind == 1 ? values : kind == 2 ? q
        : (sel == 0 ? slnw : sel == 1 ? slnb : sel == 2 ? clnw : clnb);
    src += (size_t)mat * 65536;

    const int r0 = t >> 4, c4 = (t & 15) * 4;
    if (kind == 1) {                     // identity only: V^T[b][c][l*1024+p]
      unsigned short* VTp = (unsigned short*)(ws + O_VT);
      const int b = mat >> 3, l = mat & 7;
#pragma unroll
      for (int pass = 0; pass < 4; ++pass) {
        const int r = pass * 16 + r0;
        float4 v = *(const float4*)(src + (size_t)r * 1024 + p0 + c4);
        ushort4 o;
        o.x = f2bf(v.x); o.y = f2bf(v.y); o.z = f2bf(v.z); o.w = f2bf(v.w);
        *(ushort4*)(VTp + ((size_t)b * 64 + r) * 8192 + l * 1024 + p0 + c4) = o;
      }
      return;
    }
#pragma unroll
    for (int pass = 0; pass < 4; ++pass) {
      const int r = pass * 16 + r0;
      float4 v = *(const float4*)(src + (size_t)r * 1024 + p0 + c4);
      T[r][c4] = v.x; T[r][c4 + 1] = v.y; T[r][c4 + 2] = v.z; T[r][c4 + 3] = v.w;
    }
    __syncthreads();
#pragma unroll
    for (int pass = 0; pass < 2; ++pass) {
      const int p = pass * 32 + (t >> 3), cs = (t & 7) * 8;
      short8 o;
      if (kind == 0) {                   // Ksp[b][l*1024+p][c] * LOG2E
#pragma unroll
        for (int j = 0; j < 8; ++j) o[j] = (short)f2bf(T[cs + j][p] * LOG2E);
        const int b = mat >> 3, l = mat & 7;
        *(short8*)((unsigned short*)(ws + O_KSP) +
                   ((size_t)b * 8192 + l * 1024 + p0 + p) * 64 + cs) = o;
      } else if (kind == 2) {            // Qt[b][p][c]
#pragma unroll
        for (int j = 0; j < 8; ++j) o[j] = (short)f2bf(T[cs + j][p]);
        *(short8*)((unsigned short*)(ws + O_QT) +
                   ((size_t)mat * 1024 + p0 + p) * 64 + cs) = o;
      } else {                           // LN param^T [s][p][c]
#pragma unroll
        for (int j = 0; j < 8; ++j) o[j] = (short)f2bf(T[cs + j][p]);
        unsigned long off = (sel & 1) ? O_LNB : O_LNW;
        *(short8*)((unsigned short*)(ws + off) +
                   ((size_t)(sel >> 1) * 1024 + p0 + p) * 64 + cs) = o;
      }
    }
    return;
  }

  // ---- weights ----
  {
    unsigned i = (job - 2240) * 256u + t;
    if (i < 204800u) {                   // W1t[s][off][co][ci] <- w1[co][ci][off]
      unsigned ci = i & 63u, co = (i >> 6) & 63u, tt = i >> 12;
      unsigned off = tt % 25u, st = tt / 25u;
      const float* w = st ? cw1 : sw1;
      ((unsigned short*)(ws + O_W1T))[i] = f2bf(w[(co * 64u + ci) * 25u + off]);
      return;
    }
    i -= 204800u;
    if (i < 16384u) {                    // W2b[s][nh][c]
      unsigned c = i & 63u, nh = (i >> 6) & 127u, st = i >> 13;
      const float* w = st ? cw2 : sw2;
      ((unsigned short*)(ws + O_W2B))[i] = f2bf(w[nh * 64u + c]);
    }
  }
}

// ============================================================================
// K2: chan_soft (blocks 0..31, depends only on k1's Sp) ∪ spat_attn (32..543).
// chan_soft first so its short blocks release slots to the spat tail.
// ============================================================================
__global__ __launch_bounds__(256) void k2_soft_spat(char* __restrict__ ws)
{
  __shared__ __align__(16) unsigned char SM[65536];

  if (blockIdx.x < 32) {                 // ---- chan_soft ----
    const float* Sp = (const float*)(ws + O_SP);
    unsigned short* P = (unsigned short*)(ws + O_PCH);
    const int bid = blockIdx.x;
    const int b = bid >> 2, rt = bid & 3;
    const int row = rt * 16 + (threadIdx.x >> 4), tc = threadIdx.x & 15;

    float sv[32];
    float mx = -1e30f;
#pragma unroll
    for (int jj = 0; jj < 32; ++jj) {
      const int col = jj * 16 + tc;
      size_t base = ((size_t)b * 64 + row) * 512 + col;
      float v = Sp[base] + Sp[base + 262144] + Sp[base + 524288] + Sp[base + 786432];
      sv[jj] = v;
      mx = fmaxf(mx, v);
    }
#pragma unroll
    for (int o = 1; o < 16; o <<= 1) mx = fmaxf(mx, __shfl_xor(mx, o, 64));
    float sum = 0.f;
#pragma unroll
    for (int jj = 0; jj < 32; ++jj) {
      float e = exp2fast(sv[jj] - mx);
      sv[jj] = e;
      sum += e;
    }
#pragma unroll
    for (int o = 1; o < 16; o <<= 1) sum += __shfl_xor(sum, o, 64);
    const float rs = 1.0f / sum;
#pragma unroll
    for (int jj = 0; jj < 32; ++jj)
      P[((size_t)b * 64 + row) * 512 + jj * 16 + tc] = f2bf(sv[jj] * rs);
    return;
  }

  // ================= spatial attention =================
  unsigned short (*Kt)[4096] = (unsigned short(*)[4096])(SM);
  unsigned short (*Vt)[4096] = (unsigned short(*)[4096])(SM + 16384);
  unsigned short (*Pl)[4096] = (unsigned short(*)[4096])(SM + 32768);

  const unsigned short* QT = (const unsigned short*)(ws + O_QT);
  const unsigned short* KSP = (const unsigned short*)(ws + O_KSP);
  const unsigned short* VTg = (const unsigned short*)(ws + O_VT);
  unsigned short* NUM = (unsigned short*)(ws + O_NUM);
  float* DEN = (float*)(ws + O_DEN);

  const int bid = blockIdx.x - 32;
  const int b = bid >> 6;
  const int qt = (bid >> 4) & 3;
  const int s = bid & 15;
  const int t = threadIdx.x;
  const int w = t >> 6, lane = t & 63;
  const int low4 = lane & 15, quad = lane >> 4;

  const unsigned short* KSPb = KSP + (size_t)b * 8192 * 64;
  const unsigned short* VTb = VTg + (size_t)b * 64 * 8192;
  const int qbase = qt * 256 + w * 64;
  const int kvbase = s * 512;

  int cn[2], cks[2], cqd[2], cl4[2];
#pragma unroll
  for (int pass = 0; pass < 2; ++pass) {
    const int c = pass * 256 + t;
    cn[pass] = c >> 7; cks[pass] = (c >> 6) & 1;
    cqd[pass] = (c >> 4) & 3; cl4[pass] = c & 15;
  }

  short8 qa[4][2];
#pragma unroll
  for (int mi = 0; mi < 4; ++mi)
#pragma unroll
    for (int ks = 0; ks < 2; ++ks)
      qa[mi][ks] = *(const short8*)(QT +
          ((size_t)(b * 1024 + qbase + mi * 16 + low4)) * 64 + ks * 32 + quad * 8);

  short8 vones;
#pragma unroll
  for (int j = 0; j < 8; ++j) vones[j] = (short)0x3F80;

  f4 accO[4][4], accD[4];
#pragma unroll
  for (int m = 0; m < 4; ++m) {
    accD[m] = (f4){0.f, 0.f, 0.f, 0.f};
#pragma unroll
    for (int n = 0; n < 4; ++n) accO[m][n] = (f4){0.f, 0.f, 0.f, 0.f};
  }

#pragma unroll
  for (int pass = 0; pass < 2; ++pass) {
    GLOAD_LDS16(KSPb + ((size_t)(kvbase + cn[pass] * 16 + cl4[pass])) * 64 +
                    cks[pass] * 32 + cqd[pass] * 8,
                &Kt[0][(pass * 256 + w * 64) * 8]);
    GLOAD_LDS16(VTb + ((size_t)(cn[pass] * 16 + cl4[pass])) * 8192 + kvbase +
                    cks[pass] * 32 + cqd[pass] * 8,
                &Vt[0][(pass * 256 + w * 64) * 8]);
  }

  const int pswz = ((low4 >> 2) & 3) << 1;
  for (int it = 0; it < 8; ++it) {
    const int d = it & 1;
    __syncthreads();
    if (it < 7) {
      const int kv1 = kvbase + (it + 1) * 64;
#pragma unroll
      for (int pass = 0; pass < 2; ++pass) {
        GLOAD_LDS16(KSPb + ((size_t)(kv1 + cn[pass] * 16 + cl4[pass])) * 64 +
                        cks[pass] * 32 + cqd[pass] * 8,
                    &Kt[d ^ 1][(pass * 256 + w * 64) * 8]);
        GLOAD_LDS16(VTb + ((size_t)(cn[pass] * 16 + cl4[pass])) * 8192 + kv1 +
                        cks[pass] * 32 + cqd[pass] * 8,
                    &Vt[d ^ 1][(pass * 256 + w * 64) * 8]);
      }
    }
#pragma unroll
    for (int n = 0; n < 4; ++n) {
      f4 sS[4];
#pragma unroll
      for (int mi = 0; mi < 4; ++mi) sS[mi] = (f4){0.f, 0.f, 0.f, 0.f};
#pragma unroll
      for (int ks = 0; ks < 2; ++ks) {
        short8 kb = *(const short8*)&Kt[d][((n * 2 + ks) * 64 + lane) * 8];
#pragma unroll
        for (int mi = 0; mi < 4; ++mi) sS[mi] = MFMA16(qa[mi][ks], kb, sS[mi]);
      }
      const int cpr = (((n * 2 + (low4 >> 3)) ^ (quad << 1)) << 3) + (low4 & 7);
#pragma unroll
      for (int mi = 0; mi < 4; ++mi) {
        unsigned short* pw = &Pl[w][(mi * 16 + quad * 4) * 64 + cpr];
#pragma unroll
        for (int r = 0; r < 4; ++r)
          pw[r * 64] = f2bf_rz(exp2fast(sS[mi][r]));
      }
    }
#pragma unroll
    for (int ks = 0; ks < 2; ++ks) {
      short8 vb[4];
#pragma unroll
      for (int n2 = 0; n2 < 4; ++n2)
        vb[n2] = *(const short8*)&Vt[d][((n2 * 2 + ks) * 64 + lane) * 8];
      const int cr = (((ks * 4 + quad) ^ pswz) << 3);
#pragma unroll
      for (int m = 0; m < 4; ++m) {
        short8 pa = *(const short8*)&Pl[w][(m * 16 + low4) * 64 + cr];
        accD[m] = MFMA16(pa, vones, accD[m]);
#pragma unroll
        for (int n2 = 0; n2 < 4; ++n2) accO[m][n2] = MFMA16(pa, vb[n2], accO[m][n2]);
      }
    }
  }

#pragma unroll
  for (int m = 0; m < 4; ++m)
#pragma unroll
    for (int r = 0; r < 4; ++r) {
      const int row = qbase + m * 16 + quad * 4 + r;
      const size_t base = ((size_t)(b * 1024 + row) * 16 + s);
#pragma unroll
      for (int n2 = 0; n2 < 4; ++n2)
        NUM[base * 64 + n2 * 16 + low4] = f2bf(accO[m][n2][r]);
      if (low4 == 0) DEN[base] = accD[m][r];
    }
}

// ============================================================================
// K3: chan_B (blocks 0..127) ∪ spat_fin (128..639).
// chan_B first (longer blocks, strided V gather); spat_fin is streaming.
// ============================================================================
__global__ __launch_bounds__(256) void k3_chanB_fin(
    const float* __restrict__ values, char* __restrict__ ws)
{
  if (blockIdx.x < 128) {                // ---- chan_B: O = P @ V + residual --
    const unsigned short* P = (const unsigned short*)(ws + O_PCH);
    const unsigned short* QT = (const unsigned short*)(ws + O_QT);
    unsigned short* Xc = (unsigned short*)(ws + O_XC);

    const int bid = blockIdx.x;
    const int b = bid >> 4, pt = bid & 15;
    const int w = threadIdx.x >> 6, lane = threadIdx.x & 63;
    const int low4 = lane & 15, quad = lane >> 4;
    const int p = pt * 64 + w * 16 + low4;

    f4 acc[4];
#pragma unroll
    for (int m = 0; m < 4; ++m) acc[m] = (f4){0.f, 0.f, 0.f, 0.f};

    const float* vbase = values + (size_t)b * 524288 + p;
    for (int ks = 0; ks < 16; ++ks) {
      short8 vbv;
      const float* vp = vbase + (size_t)(ks * 32 + quad * 8) * 1024;
#pragma unroll
      for (int j = 0; j < 8; ++j) vbv[j] = (short)f2bf(vp[(size_t)j * 1024]);
#pragma unroll
      for (int m = 0; m < 4; ++m) {
        short8 a = *(const short8*)(P + ((size_t)(b * 64 + m * 16 + low4)) * 512 + ks * 32 + quad * 8);
        acc[m] = MFMA16(a, vbv, acc[m]);
      }
    }
#pragma unroll
    for (int m = 0; m < 4; ++m)
#pragma unroll
      for (int r = 0; r < 4; ++r) {
        const int c = m * 16 + quad * 4 + r;
        size_t o = ((size_t)(b * 1024 + p)) * 64 + c;
        Xc[o] = f2bf(acc[m][r] + bf2f(QT[o]));
      }
    return;
  }

  // ---- spat_fin: sum 16 bf16 partials, normalize, +residual -> Xs ----
  {
    const unsigned short* NUM = (const unsigned short*)(ws + O_NUM);
    const float* DEN = (const float*)(ws + O_DEN);
    const unsigned short* QT = (const unsigned short*)(ws + O_QT);
    unsigned short* Xs = (unsigned short*)(ws + O_XS);

    const unsigned i = (blockIdx.x - 128) * 256u + threadIdx.x;   // 131072
    const int c0 = (i & 15) * 4;
    const unsigned row = i >> 4;                          // [0, 8192)

    float dtot = 0.f;
#pragma unroll
    for (int sq = 0; sq < 4; ++sq) {
      float4 dv = *(const float4*)(DEN + (size_t)row * 16 + sq * 4);
      dtot += dv.x + dv.y + dv.z + dv.w;
    }
    float n4[4] = {0.f, 0.f, 0.f, 0.f};
#pragma unroll
    for (int s = 0; s < 16; ++s) {
      ushort4 pv = *(const ushort4*)(NUM + ((size_t)row * 16 + s) * 64 + c0);
      n4[0] += bf2f(pv.x); n4[1] += bf2f(pv.y);
      n4[2] += bf2f(pv.z); n4[3] += bf2f(pv.w);
    }
    const float rd = 1.0f / dtot;
    size_t ob = (size_t)row * 64 + c0;
    ushort4 qv = *(const ushort4*)(QT + ob);
    ushort4 o4;
    o4.x = f2bf(n4[0] * rd + bf2f(qv.x));
    o4.y = f2bf(n4[1] * rd + bf2f(qv.y));
    o4.z = f2bf(n4[2] * rd + bf2f(qv.z));
    o4.w = f2bf(n4[3] * rd + bf2f(qv.w));
    *(ushort4*)(Xs + ob) = o4;
  }
}

// ---------------- conv5 body (one stem): bid in [0,256) --------------------
__device__ __forceinline__ void conv5_body(char* ws, const float* b1p, int s, int bid)
{
  __shared__ float Hbuf[2][16][65];
  __shared__ float red[2][2];

  const int b = bid >> 5, pt = bid & 31;
  const int w = threadIdx.x >> 6, lane = threadIdx.x & 63;
  const int low4 = lane & 15, quad = lane >> 4;
  const int wsub = w & 1, half = w >> 1;

  const unsigned short* X = (const unsigned short*)(ws + (s ? O_XC : O_XS));
  const unsigned short* W1t = (const unsigned short*)(ws + O_W1T);
  unsigned short* Yt = (unsigned short*)(ws + O_YT);
  float* stats = (float*)(ws + O_STATS);

  const int p = pt * 32 + wsub * 16 + low4;
  const int y0 = p >> 5, x0 = p & 31;

  f4 acc[4];
#pragma unroll
  for (int m = 0; m < 4; ++m) acc[m] = (f4){0.f, 0.f, 0.f, 0.f};

  const int o0 = half ? 13 : 0, o1 = half ? 25 : 13;
  for (int off = o0; off < o1; ++off) {
    const int dy = off / 5 - 2, dx = off % 5 - 2;
    const int ys = y0 + dy, xs = x0 + dx;
    const bool valid = ((unsigned)ys < 32u) & ((unsigned)xs < 32u);
    const int psrc = valid ? (p + dy * 32 + dx) : p;
    const unsigned short* xp = X + ((size_t)(b * 1024 + psrc)) * 64;
    const unsigned short* wp = W1t + ((size_t)((s * 25 + off) * 64)) * 64;
#pragma unroll
    for (int ks = 0; ks < 2; ++ks) {
      short8 bv = *(const short8*)(xp + ks * 32 + quad * 8);
      if (!valid) bv = (short8)0;
#pragma unroll
      for (int m = 0; m < 4; ++m) {
        short8 av = *(const short8*)(wp + (m * 16 + low4) * 64 + ks * 32 + quad * 8);
        acc[m] = MFMA16(av, bv, acc[m]);
      }
    }
  }

  if (half) {
#pragma unroll
    for (int m = 0; m < 4; ++m)
#pragma unroll
      for (int r = 0; r < 4; ++r)
        Hbuf[wsub][low4][m * 16 + quad * 4 + r] = acc[m][r];
  }
  __syncthreads();
  if (!half) {
    float ls = 0.f, ls2 = 0.f;
#pragma unroll
    for (int m = 0; m < 4; ++m)
#pragma unroll
      for (int r = 0; r < 4; ++r) {
        const int co = m * 16 + quad * 4 + r;
        float y = acc[m][r] + Hbuf[wsub][low4][co] + b1p[co];
        Yt[((size_t)((s * 8 + b) * 1024 + p)) * 64 + co] = f2bf(y);
        ls += y; ls2 += y * y;
      }
#pragma unroll
    for (int o = 1; o < 64; o <<= 1) {
      ls += __shfl_xor(ls, o, 64);
      ls2 += __shfl_xor(ls2, o, 64);
    }
    if (lane == 0) { red[0][wsub] = ls; red[1][wsub] = ls2; }
  }
  __syncthreads();
  if (threadIdx.x == 0) {
    atomicAdd(&stats[(s * 8 + b) * 2 + 0], red[0][0] + red[0][1]);
    atomicAdd(&stats[(s * 8 + b) * 2 + 1], red[1][0] + red[1][1]);
  }
}

// ---------------- final body (one stem): bid in [0,256) --------------------
__device__ __forceinline__ void final_body(char* ws, const float* b2p,
                                           float* out, int s, int bid)
{
  const int b = bid >> 5, pt = bid & 31;
  const int w = threadIdx.x >> 6, lane = threadIdx.x & 63;
  const int low4 = lane & 15, quad = lane >> 4;
  const int p2 = pt * 32 + (w & 1) * 16 + low4;
  const int nh0 = (w >> 1) * 64;

  const unsigned short* Yt = (const unsigned short*)(ws + O_YT);
  const unsigned short* LNW = (const unsigned short*)(ws + O_LNW);
  const unsigned short* LNB = (const unsigned short*)(ws + O_LNB);
  const unsigned short* W2b = (const unsigned short*)(ws + O_W2B);
  const float* stats = (const float*)(ws + O_STATS);

  const float inv = 1.0f / 65536.0f;
  const float mu = stats[(s * 8 + b) * 2 + 0] * inv;
  const float ms = stats[(s * 8 + b) * 2 + 1] * inv;
  const float rsig = rsqrtf(ms - mu * mu + 1e-5f);

  f4 acc[4];
#pragma unroll
  for (int m = 0; m < 4; ++m) acc[m] = (f4){0.f, 0.f, 0.f, 0.f};

#pragma unroll
  for (int ks = 0; ks < 2; ++ks) {
    size_t yo = ((size_t)((s * 8 + b) * 1024 + p2)) * 64 + ks * 32 + quad * 8;
    size_t lo = ((size_t)(s * 1024 + p2)) * 64 + ks * 32 + quad * 8;
    short8 yv = *(const short8*)(Yt + yo);
    short8 lw8 = *(const short8*)(LNW + lo);
    short8 lb8 = *(const short8*)(LNB + lo);
    short8 zv;
#pragma unroll
    for (int j = 0; j < 8; ++j) {
      float z = (bf2f((unsigned short)yv[j]) - mu) * rsig * bf2f((unsigned short)lw8[j]) +
                bf2f((unsigned short)lb8[j]);
      zv[j] = (short)f2bf(fmaxf(z, 0.f));
    }
#pragma unroll
    for (int m = 0; m < 4; ++m) {
      short8 a = *(const short8*)(W2b + ((size_t)(s * 128 + nh0 + m * 16 + low4)) * 64 + ks * 32 + quad * 8);
      acc[m] = MFMA16(a, zv, acc[m]);
    }
  }
#pragma unroll
  for (int m = 0; m < 4; ++m)
#pragma unroll
    for (int r = 0; r < 4; ++r) {
      const int nh = nh0 + m * 16 + quad * 4 + r;
      out[((size_t)((s * 8 + b) * 128 + nh)) * 1024 + p2] = acc[m][r] + b2p[nh];
    }
}

// ============================================================================
// K4: conv5-spatial (0..255) ∪ conv5-channel (256..511) -- perfect 2/CU.
// ============================================================================
__global__ __launch_bounds__(256) void k4_conv5(
    char* __restrict__ ws, const float* __restrict__ sb1,
    const float* __restrict__ cb1)
{
  if (blockIdx.x < 256) conv5_body(ws, sb1, 0, blockIdx.x);
  else                  conv5_body(ws, cb1, 1, blockIdx.x - 256);
}

// ============================================================================
// K5: final-spatial (0..255) ∪ final-channel (256..511) -- perfect 2/CU.
// ============================================================================
__global__ __launch_bounds__(256) void k5_final(
    char* __restrict__ ws, const float* __restrict__ sb2,
    const float* __restrict__ cb2, float* __restrict__ out)
{
  if (blockIdx.x < 256) final_body(ws, sb2, out, 0, blockIdx.x);
  else                  final_body(ws, cb2, out, 1, blockIdx.x - 256);
}

extern "C" void kernel_launch(void* const* d_in, const int* in_sizes, int n_in,
                              void* d_out, int out_size, void* d_ws, size_t ws_size,
                              hipStream_t stream)
{
  const float* q    = (const float*)d_in[0];
  const float* keys = (const float*)d_in[1];
  const float* vals = (const float*)d_in[2];
  const float* sw1  = (const float*)d_in[3];
  const float* sb1  = (const float*)d_in[4];
  const float* slnw = (const float*)d_in[5];
  const float* slnb = (const float*)d_in[6];
  const float* sw2  = (const float*)d_in[7];
  const float* sb2  = (const float*)d_in[8];
  const float* cw1  = (const float*)d_in[9];
  const float* cb1  = (const float*)d_in[10];
  const float* clnw = (const float*)d_in[11];
  const float* clnb = (const float*)d_in[12];
  const float* cw2  = (const float*)d_in[13];
  const float* cb2  = (const float*)d_in[14];
  char* ws = (char*)d_ws;

  k1_prep<<<3232, 256, 0, stream>>>(q, keys, vals, sw1, slnw, slnb, sw2,
                                    cw1, clnw, clnb, cw2, ws);
  k2_soft_spat<<<544, 256, 0, stream>>>(ws);
  k3_chanB_fin<<<640, 256, 0, stream>>>(vals, ws);
  k4_conv5<<<512, 256, 0, stream>>>(ws, sb1, cb1);
  k5_final<<<512, 256, 0, stream>>>(ws, sb2, cb2, (float*)d_out);
}

// Round 4
// 201.751 us; speedup vs baseline: 1.0429x; 1.0174x over previous
//
#include <hip/hip_runtime.h>

// ---------------------------------------------------------------------------
// DualAttention on MI355X.  B=8 L=8 C=64 W=32 (WH=1024, LWH=8192) NH=128 FS=5
// R11: k2 retiled to kv-split 8 x qt-split 8 (was 16 x 4).  Same 512 blocks,
//   same staging traffic, but per-wave P tile 32x64 -> Pl 16KB -> LDS 48KB ->
//   3 blocks/CU (was 2), and NUM partials 16->8 (halves k2 write / k3 read).
//   R7 inner-loop phase structure preserved (full 4-n S phase -> 2-ks PV,
//   XOR-swizzled Pl, dbuf, 1 barrier/iter) -- avoids the R8 ILP trap.
// Pipeline: k1 = chanS ∪ prep | k2 = chan_soft ∪ spat | k3 = chanB ∪ spat_fin
//           | k4 = conv5 x2 | k5 = final x2.
// ---------------------------------------------------------------------------

#define LOG2E 1.44269504088896340736f

typedef __attribute__((ext_vector_type(8))) short short8;   // bf16 x8 frag
typedef __attribute__((ext_vector_type(4))) float f4;       // fp32 x4 frag

#define MFMA16(a, b, c) __builtin_amdgcn_mfma_f32_16x16x32_bf16(a, b, c, 0, 0, 0)

#define GLOAD_LDS16(gp, lp) __builtin_amdgcn_global_load_lds( \
    (const __attribute__((address_space(1))) void*)(gp), \
    (__attribute__((address_space(3))) void*)(lp), 16, 0, 0)

__device__ __forceinline__ unsigned short f2bf(float f) {   // RNE float->bf16
  union { float f; unsigned u; } v; v.f = f;
  unsigned r = v.u + 0x7FFFu + ((v.u >> 16) & 1u);
  return (unsigned short)(r >> 16);
}
__device__ __forceinline__ unsigned short f2bf_rz(float f) { // truncate (P only)
  union { float f; unsigned u; } v; v.f = f;
  return (unsigned short)(v.u >> 16);
}
__device__ __forceinline__ float bf2f(unsigned short h) {
  union { unsigned u; float f; } v; v.u = ((unsigned)h) << 16;
  return v.f;
}
__device__ __forceinline__ float exp2fast(float x) {
#if __has_builtin(__builtin_amdgcn_exp2f)
  return __builtin_amdgcn_exp2f(x);
#else
  return exp2f(x);
#endif
}

// ---------------- workspace layout (bytes), total ~45.0MB ------------------
#define O_STATS 0ul                      // [2][8][2] f32 (zeroed in k1)
#define O_W1T   256ul                    // [2][25][64][64] bf16
#define O_W2B   409856ul                 // [2][128][64] bf16
#define O_LNW   442624ul                 // [2][1024][64] bf16 (transposed lnw)
#define O_LNB   704768ul                 // [2][1024][64] bf16
#define O_QT    966912ul                 // [8][1024][64] bf16  q^T
#define O_KSP   2015488ul                // [8][8192][64] bf16  spatial K *LOG2E
#define O_VT    10404096ul               // [8][64][8192] bf16  spatial V^T
#define O_NUM   18792704ul               // [8][1024][8][64] bf16 spat num part
#define O_DEN   35569920ul               // [8][1024][8] f32      spat den part
#define O_SP    36094208ul               // [4][8][64][512] f32 chan S partials
#define O_PCH   40288512ul               // [8][64][512] bf16   chan P
#define O_XS    40812800ul               // [8][1024][64] bf16 stem in (spatial)
#define O_XC    41861376ul               // [8][1024][64] bf16 stem in (channel)
#define O_YT    42909952ul               // [2][8][1024][64] bf16 conv1 out

// ============================================================================
// K1: chan_S GEMM (blocks 0..127) ∪ tile/LN/weight prep (128..3231).
// ============================================================================
__global__ __launch_bounds__(256) void k1_prep(
    const float* __restrict__ q, const float* __restrict__ keys,
    const float* __restrict__ values,
    const float* __restrict__ sw1, const float* __restrict__ slnw,
    const float* __restrict__ slnb, const float* __restrict__ sw2,
    const float* __restrict__ cw1, const float* __restrict__ clnw,
    const float* __restrict__ clnb, const float* __restrict__ cw2,
    char* __restrict__ ws)
{
  __shared__ __align__(16) unsigned char SM1[49152];   // chanS dbuf / prep T
  const int t = threadIdx.x;

  if (blockIdx.x < 128) {                // ================= chan_S ==========
    float* Sp = (float*)(ws + O_SP);
    const int bid = blockIdx.x;
    if (bid == 0 && t < 64) ((float*)(ws + O_STATS))[t] = 0.f;
    const int b = bid >> 4, colT = (bid >> 2) & 3, kt = bid & 3;
    const int w = t >> 6, lane = t & 63;
    const int low4 = lane & 15, quad = lane >> 4;
    const int dl = lane >> 1, dh = lane & 1;
    const int k00 = kt * 256;

    // buf layout (per buf, 24576B): K f32 tile at +0 (16KB), Q at +16384 (8KB)
    f4 acc[4][2];
#pragma unroll
    for (int m = 0; m < 4; ++m)
#pragma unroll
      for (int n = 0; n < 2; ++n) acc[m][n] = (f4){0.f, 0.f, 0.f, 0.f};

    auto stageAll = [&](int bo, int k0) {
#pragma unroll
      for (int gi = 0; gi < 4; ++gi) {           // K: groups w, w+4, w+8, w+12
        const int g = w + gi * 4;
        const int n = g >> 1, sub = g & 1;
        const int l = sub * 32 + dl;
        const float* gp = keys + (size_t)(b * 512 + colT * 128 + n * 16 + (l & 15)) * 1024
                          + k0 + (l >> 4) * 8 + dh * 4;
        GLOAD_LDS16(gp, SM1 + bo + (size_t)(n * 128 + sub * 64) * 16);
      }
#pragma unroll
      for (int gi = 0; gi < 2; ++gi) {           // Q: groups w, w+4
        const int g = w + gi * 4;
        const int m = g >> 1, sub = g & 1;
        const int l = sub * 32 + dl;
        const float* gp = q + (size_t)(b * 64 + m * 16 + (l & 15)) * 1024
                          + k0 + (l >> 4) * 8 + dh * 4;
        GLOAD_LDS16(gp, SM1 + bo + 16384 + (size_t)(m * 128 + sub * 64) * 16);
      }
    };

    stageAll(0, k00);
    for (int it = 0; it < 8; ++it) {
      const int bo = (it & 1) * 24576;
      const char* cb = (const char*)SM1 + bo;
      __syncthreads();
      if (it < 7) stageAll(bo ^ 24576, k00 + (it + 1) * 32);

      short8 ah[4], al[4];
#pragma unroll
      for (int m = 0; m < 4; ++m) {              // A-frags from LDS, *LOG2E, split
        const float* fp = (const float*)(cb + 16384 + (size_t)(m * 128 + lane * 2) * 16);
        float4 u0 = ((const float4*)fp)[0];
        float4 u1 = ((const float4*)fp)[1];
        float vv[8] = {u0.x, u0.y, u0.z, u0.w, u1.x, u1.y, u1.z, u1.w};
#pragma unroll
        for (int j = 0; j < 8; ++j) {
          float sv = vv[j] * LOG2E;
          unsigned short hi = f2bf(sv);
          ah[m][j] = (short)hi;
          al[m][j] = (short)f2bf(sv - bf2f(hi));
        }
      }
#pragma unroll
      for (int n2 = 0; n2 < 2; ++n2) {           // B-frags (this wave's 2 n-tiles)
        const int n = w * 2 + n2;
        const float* fp = (const float*)(cb + (size_t)(n * 128 + lane * 2) * 16);
        float4 u0 = ((const float4*)fp)[0];
        float4 u1 = ((const float4*)fp)[1];
        float vv[8] = {u0.x, u0.y, u0.z, u0.w, u1.x, u1.y, u1.z, u1.w};
        short8 bh, bl;
#pragma unroll
        for (int j = 0; j < 8; ++j) {
          unsigned short hi = f2bf(vv[j]);
          bh[j] = (short)hi;
          bl[j] = (short)f2bf(vv[j] - bf2f(hi));
        }
#pragma unroll
        for (int m = 0; m < 4; ++m) {
          acc[m][n2] = MFMA16(ah[m], bh, acc[m][n2]);
          acc[m][n2] = MFMA16(al[m], bh, acc[m][n2]);
          acc[m][n2] = MFMA16(ah[m], bl, acc[m][n2]);
        }
      }
    }

#pragma unroll
    for (int m = 0; m < 4; ++m)
#pragma unroll
      for (int n2 = 0; n2 < 2; ++n2)
#pragma unroll
        for (int r = 0; r < 4; ++r) {
          const int row = m * 16 + quad * 4 + r;
          const int col = colT * 128 + (w * 2 + n2) * 16 + low4;
          Sp[(((size_t)kt * 8 + b) * 64 + row) * 512 + col] = acc[m][n2][r];
        }
    return;
  }

  // ================= prep jobs =================
  float (*T)[65] = (float(*)[65])SM1;
  const int job = blockIdx.x - 128;

  if (job < 2240) {                      // ---- tile jobs ----
    int kind, mat = 0, sel = 0;
    if (job < 1024)      { kind = 0; mat = job >> 4; }
    else if (job < 2048) { kind = 1; mat = (job - 1024) >> 4; }
    else if (job < 2176) { kind = 2; mat = (job - 2048) >> 4; }
    else                 { kind = 3; sel = (job - 2176) >> 4; }
    const int pt = job & 15, p0 = pt * 64;
    const float* src =
        kind == 0 ? keys : kind == 1 ? values : kind == 2 ? q
        : (sel == 0 ? slnw : sel == 1 ? slnb : sel == 2 ? clnw : clnb);
    src += (size_t)mat * 65536;

    const int r0 = t >> 4, c4 = (t & 15) * 4;
    if (kind == 1) {                     // identity only: V^T[b][c][l*1024+p]
      unsigned short* VTp = (unsigned short*)(ws + O_VT);
      const int b = mat >> 3, l = mat & 7;
#pragma unroll
      for (int pass = 0; pass < 4; ++pass) {
        const int r = pass * 16 + r0;
        float4 v = *(const float4*)(src + (size_t)r * 1024 + p0 + c4);
        ushort4 o;
        o.x = f2bf(v.x); o.y = f2bf(v.y); o.z = f2bf(v.z); o.w = f2bf(v.w);
        *(ushort4*)(VTp + ((size_t)b * 64 + r) * 8192 + l * 1024 + p0 + c4) = o;
      }
      return;
    }
#pragma unroll
    for (int pass = 0; pass < 4; ++pass) {
      const int r = pass * 16 + r0;
      float4 v = *(const float4*)(src + (size_t)r * 1024 + p0 + c4);
      T[r][c4] = v.x; T[r][c4 + 1] = v.y; T[r][c4 + 2] = v.z; T[r][c4 + 3] = v.w;
    }
    __syncthreads();
#pragma unroll
    for (int pass = 0; pass < 2; ++pass) {
      const int p = pass * 32 + (t >> 3), cs = (t & 7) * 8;
      short8 o;
      if (kind == 0) {                   // Ksp[b][l*1024+p][c] * LOG2E
#pragma unroll
        for (int j = 0; j < 8; ++j) o[j] = (short)f2bf(T[cs + j][p] * LOG2E);
        const int b = mat >> 3, l = mat & 7;
        *(short8*)((unsigned short*)(ws + O_KSP) +
                   ((size_t)b * 8192 + l * 1024 + p0 + p) * 64 + cs) = o;
      } else if (kind == 2) {            // Qt[b][p][c]
#pragma unroll
        for (int j = 0; j < 8; ++j) o[j] = (short)f2bf(T[cs + j][p]);
        *(short8*)((unsigned short*)(ws + O_QT) +
                   ((size_t)mat * 1024 + p0 + p) * 64 + cs) = o;
      } else {                           // LN param^T [s][p][c]
#pragma unroll
        for (int j = 0; j < 8; ++j) o[j] = (short)f2bf(T[cs + j][p]);
        unsigned long off = (sel & 1) ? O_LNB : O_LNW;
        *(short8*)((unsigned short*)(ws + off) +
                   ((size_t)(sel >> 1) * 1024 + p0 + p) * 64 + cs) = o;
      }
    }
    return;
  }

  // ---- weights ----
  {
    unsigned i = (job - 2240) * 256u + t;
    if (i < 204800u) {                   // W1t[s][off][co][ci] <- w1[co][ci][off]
      unsigned ci = i & 63u, co = (i >> 6) & 63u, tt = i >> 12;
      unsigned off = tt % 25u, st = tt / 25u;
      const float* w = st ? cw1 : sw1;
      ((unsigned short*)(ws + O_W1T))[i] = f2bf(w[(co * 64u + ci) * 25u + off]);
      return;
    }
    i -= 204800u;
    if (i < 16384u) {                    // W2b[s][nh][c]
      unsigned c = i & 63u, nh = (i >> 6) & 127u, st = i >> 13;
      const float* w = st ? cw2 : sw2;
      ((unsigned short*)(ws + O_W2B))[i] = f2bf(w[nh * 64u + c]);
    }
  }
}

// ============================================================================
// K2: chan_soft (blocks 0..31) ∪ spat_attn (32..543).
// spat: kv-split 8 x qt-split 8.  Per block: 128 q rows x 1024 kv, 16 iters.
// Per wave: 32 q rows (M=2).  LDS 48KB (Kt 16 + Vt 16 + Pl 16) -> 3 blk/CU.
// ============================================================================
__global__ __launch_bounds__(256) void k2_soft_spat(char* __restrict__ ws)
{
  __shared__ __align__(16) unsigned char SM[49152];

  if (blockIdx.x < 32) {                 // ---- chan_soft ----
    const float* Sp = (const float*)(ws + O_SP);
    unsigned short* P = (unsigned short*)(ws + O_PCH);
    const int bid = blockIdx.x;
    const int b = bid >> 2, rt = bid & 3;
    const int row = rt * 16 + (threadIdx.x >> 4), tc = threadIdx.x & 15;

    float sv[32];
    float mx = -1e30f;
#pragma unroll
    for (int jj = 0; jj < 32; ++jj) {
      const int col = jj * 16 + tc;
      size_t base = ((size_t)b * 64 + row) * 512 + col;
      float v = Sp[base] + Sp[base + 262144] + Sp[base + 524288] + Sp[base + 786432];
      sv[jj] = v;
      mx = fmaxf(mx, v);
    }
#pragma unroll
    for (int o = 1; o < 16; o <<= 1) mx = fmaxf(mx, __shfl_xor(mx, o, 64));
    float sum = 0.f;
#pragma unroll
    for (int jj = 0; jj < 32; ++jj) {
      float e = exp2fast(sv[jj] - mx);
      sv[jj] = e;
      sum += e;
    }
#pragma unroll
    for (int o = 1; o < 16; o <<= 1) sum += __shfl_xor(sum, o, 64);
    const float rs = 1.0f / sum;
#pragma unroll
    for (int jj = 0; jj < 32; ++jj)
      P[((size_t)b * 64 + row) * 512 + jj * 16 + tc] = f2bf(sv[jj] * rs);
    return;
  }

  // ================= spatial attention =================
  unsigned short (*Kt)[4096] = (unsigned short(*)[4096])(SM);
  unsigned short (*Vt)[4096] = (unsigned short(*)[4096])(SM + 16384);
  unsigned short (*Pl)[2048] = (unsigned short(*)[2048])(SM + 32768);

  const unsigned short* QT = (const unsigned short*)(ws + O_QT);
  const unsigned short* KSP = (const unsigned short*)(ws + O_KSP);
  const unsigned short* VTg = (const unsigned short*)(ws + O_VT);
  unsigned short* NUM = (unsigned short*)(ws + O_NUM);
  float* DEN = (float*)(ws + O_DEN);

  const int bid = blockIdx.x - 32;
  const int b = bid >> 6;
  const int qt = (bid >> 3) & 7;
  const int s = bid & 7;
  const int t = threadIdx.x;
  const int w = t >> 6, lane = t & 63;
  const int low4 = lane & 15, quad = lane >> 4;

  const unsigned short* KSPb = KSP + (size_t)b * 8192 * 64;
  const unsigned short* VTb = VTg + (size_t)b * 64 * 8192;
  const int qbase = qt * 128 + w * 32;
  const int kvbase = s * 1024;

  int cn[2], cks[2], cqd[2], cl4[2];
#pragma unroll
  for (int pass = 0; pass < 2; ++pass) {
    const int c = pass * 256 + t;
    cn[pass] = c >> 7; cks[pass] = (c >> 6) & 1;
    cqd[pass] = (c >> 4) & 3; cl4[pass] = c & 15;
  }

  short8 qa[2][2];
#pragma unroll
  for (int mi = 0; mi < 2; ++mi)
#pragma unroll
    for (int ks = 0; ks < 2; ++ks)
      qa[mi][ks] = *(const short8*)(QT +
          ((size_t)(b * 1024 + qbase + mi * 16 + low4)) * 64 + ks * 32 + quad * 8);

  short8 vones;
#pragma unroll
  for (int j = 0; j < 8; ++j) vones[j] = (short)0x3F80;

  f4 accO[2][4], accD[2];
#pragma unroll
  for (int m = 0; m < 2; ++m) {
    accD[m] = (f4){0.f, 0.f, 0.f, 0.f};
#pragma unroll
    for (int n = 0; n < 4; ++n) accO[m][n] = (f4){0.f, 0.f, 0.f, 0.f};
  }

#pragma unroll
  for (int pass = 0; pass < 2; ++pass) {
    GLOAD_LDS16(KSPb + ((size_t)(kvbase + cn[pass] * 16 + cl4[pass])) * 64 +
                    cks[pass] * 32 + cqd[pass] * 8,
                &Kt[0][(pass * 256 + w * 64) * 8]);
    GLOAD_LDS16(VTb + ((size_t)(cn[pass] * 16 + cl4[pass])) * 8192 + kvbase +
                    cks[pass] * 32 + cqd[pass] * 8,
                &Vt[0][(pass * 256 + w * 64) * 8]);
  }

  const int pswz = ((low4 >> 2) & 3) << 1;
  for (int it = 0; it < 16; ++it) {
    const int d = it & 1;
    __syncthreads();
    if (it < 15) {
      const int kv1 = kvbase + (it + 1) * 64;
#pragma unroll
      for (int pass = 0; pass < 2; ++pass) {
        GLOAD_LDS16(KSPb + ((size_t)(kv1 + cn[pass] * 16 + cl4[pass])) * 64 +
                        cks[pass] * 32 + cqd[pass] * 8,
                    &Kt[d ^ 1][(pass * 256 + w * 64) * 8]);
        GLOAD_LDS16(VTb + ((size_t)(cn[pass] * 16 + cl4[pass])) * 8192 + kv1 +
                        cks[pass] * 32 + cqd[pass] * 8,
                    &Vt[d ^ 1][(pass * 256 + w * 64) * 8]);
      }
    }
#pragma unroll
    for (int n = 0; n < 4; ++n) {
      f4 sS[2];
#pragma unroll
      for (int mi = 0; mi < 2; ++mi) sS[mi] = (f4){0.f, 0.f, 0.f, 0.f};
#pragma unroll
      for (int ks = 0; ks < 2; ++ks) {
        short8 kb = *(const short8*)&Kt[d][((n * 2 + ks) * 64 + lane) * 8];
#pragma unroll
        for (int mi = 0; mi < 2; ++mi) sS[mi] = MFMA16(qa[mi][ks], kb, sS[mi]);
      }
      const int cpr = (((n * 2 + (low4 >> 3)) ^ (quad << 1)) << 3) + (low4 & 7);
#pragma unroll
      for (int mi = 0; mi < 2; ++mi) {
        unsigned short* pw = &Pl[w][(mi * 16 + quad * 4) * 64 + cpr];
#pragma unroll
        for (int r = 0; r < 4; ++r)
          pw[r * 64] = f2bf_rz(exp2fast(sS[mi][r]));
      }
    }
#pragma unroll
    for (int ks = 0; ks < 2; ++ks) {
      short8 vb[4];
#pragma unroll
      for (int n2 = 0; n2 < 4; ++n2)
        vb[n2] = *(const short8*)&Vt[d][((n2 * 2 + ks) * 64 + lane) * 8];
      const int cr = (((ks * 4 + quad) ^ pswz) << 3);
#pragma unroll
      for (int m = 0; m < 2; ++m) {
        short8 pa = *(const short8*)&Pl[w][(m * 16 + low4) * 64 + cr];
        accD[m] = MFMA16(pa, vones, accD[m]);
#pragma unroll
        for (int n2 = 0; n2 < 4; ++n2) accO[m][n2] = MFMA16(pa, vb[n2], accO[m][n2]);
      }
    }
  }

#pragma unroll
  for (int m = 0; m < 2; ++m)
#pragma unroll
    for (int r = 0; r < 4; ++r) {
      const int row = qbase + m * 16 + quad * 4 + r;
      const size_t base = ((size_t)(b * 1024 + row) * 8 + s);
#pragma unroll
      for (int n2 = 0; n2 < 4; ++n2)
        NUM[base * 64 + n2 * 16 + low4] = f2bf(accO[m][n2][r]);
      if (low4 == 0) DEN[base] = accD[m][r];
    }
}

// ============================================================================
// K3: chan_B (blocks 0..127) ∪ spat_fin (128..639).
// ============================================================================
__global__ __launch_bounds__(256) void k3_chanB_fin(
    const float* __restrict__ values, char* __restrict__ ws)
{
  if (blockIdx.x < 128) {                // ---- chan_B: O = P @ V + residual --
    const unsigned short* P = (const unsigned short*)(ws + O_PCH);
    const unsigned short* QT = (const unsigned short*)(ws + O_QT);
    unsigned short* Xc = (unsigned short*)(ws + O_XC);

    const int bid = blockIdx.x;
    const int b = bid >> 4, pt = bid & 15;
    const int w = threadIdx.x >> 6, lane = threadIdx.x & 63;
    const int low4 = lane & 15, quad = lane >> 4;
    const int p = pt * 64 + w * 16 + low4;

    f4 acc[4];
#pragma unroll
    for (int m = 0; m < 4; ++m) acc[m] = (f4){0.f, 0.f, 0.f, 0.f};

    const float* vbase = values + (size_t)b * 524288 + p;
    for (int ks = 0; ks < 16; ++ks) {
      short8 vbv;
      const float* vp = vbase + (size_t)(ks * 32 + quad * 8) * 1024;
#pragma unroll
      for (int j = 0; j < 8; ++j) vbv[j] = (short)f2bf(vp[(size_t)j * 1024]);
#pragma unroll
      for (int m = 0; m < 4; ++m) {
        short8 a = *(const short8*)(P + ((size_t)(b * 64 + m * 16 + low4)) * 512 + ks * 32 + quad * 8);
        acc[m] = MFMA16(a, vbv, acc[m]);
      }
    }
#pragma unroll
    for (int m = 0; m < 4; ++m)
#pragma unroll
      for (int r = 0; r < 4; ++r) {
        const int c = m * 16 + quad * 4 + r;
        size_t o = ((size_t)(b * 1024 + p)) * 64 + c;
        Xc[o] = f2bf(acc[m][r] + bf2f(QT[o]));
      }
    return;
  }

  // ---- spat_fin: sum 8 bf16 partials, normalize, +residual -> Xs ----
  {
    const unsigned short* NUM = (const unsigned short*)(ws + O_NUM);
    const float* DEN = (const float*)(ws + O_DEN);
    const unsigned short* QT = (const unsigned short*)(ws + O_QT);
    unsigned short* Xs = (unsigned short*)(ws + O_XS);

    const unsigned i = (blockIdx.x - 128) * 256u + threadIdx.x;   // 131072
    const int c0 = (i & 15) * 4;
    const unsigned row = i >> 4;                          // [0, 8192)

    float dtot = 0.f;
#pragma unroll
    for (int sq = 0; sq < 2; ++sq) {
      float4 dv = *(const float4*)(DEN + (size_t)row * 8 + sq * 4);
      dtot += dv.x + dv.y + dv.z + dv.w;
    }
    float n4[4] = {0.f, 0.f, 0.f, 0.f};
#pragma unroll
    for (int s = 0; s < 8; ++s) {
      ushort4 pv = *(const ushort4*)(NUM + ((size_t)row * 8 + s) * 64 + c0);
      n4[0] += bf2f(pv.x); n4[1] += bf2f(pv.y);
      n4[2] += bf2f(pv.z); n4[3] += bf2f(pv.w);
    }
    const float rd = 1.0f / dtot;
    size_t ob = (size_t)row * 64 + c0;
    ushort4 qv = *(const ushort4*)(QT + ob);
    ushort4 o4;
    o4.x = f2bf(n4[0] * rd + bf2f(qv.x));
    o4.y = f2bf(n4[1] * rd + bf2f(qv.y));
    o4.z = f2bf(n4[2] * rd + bf2f(qv.z));
    o4.w = f2bf(n4[3] * rd + bf2f(qv.w));
    *(ushort4*)(Xs + ob) = o4;
  }
}

// ---------------- conv5 body (one stem): bid in [0,256) --------------------
__device__ __forceinline__ void conv5_body(char* ws, const float* b1p, int s, int bid)
{
  __shared__ float Hbuf[2][16][65];
  __shared__ float red[2][2];

  const int b = bid >> 5, pt = bid & 31;
  const int w = threadIdx.x >> 6, lane = threadIdx.x & 63;
  const int low4 = lane & 15, quad = lane >> 4;
  const int wsub = w & 1, half = w >> 1;

  const unsigned short* X = (const unsigned short*)(ws + (s ? O_XC : O_XS));
  const unsigned short* W1t = (const unsigned short*)(ws + O_W1T);
  unsigned short* Yt = (unsigned short*)(ws + O_YT);
  float* stats = (float*)(ws + O_STATS);

  const int p = pt * 32 + wsub * 16 + low4;
  const int y0 = p >> 5, x0 = p & 31;

  f4 acc[4];
#pragma unroll
  for (int m = 0; m < 4; ++m) acc[m] = (f4){0.f, 0.f, 0.f, 0.f};

  const int o0 = half ? 13 : 0, o1 = half ? 25 : 13;
  for (int off = o0; off < o1; ++off) {
    const int dy = off / 5 - 2, dx = off % 5 - 2;
    const int ys = y0 + dy, xs = x0 + dx;
    const bool valid = ((unsigned)ys < 32u) & ((unsigned)xs < 32u);
    const int psrc = valid ? (p + dy * 32 + dx) : p;
    const unsigned short* xp = X + ((size_t)(b * 1024 + psrc)) * 64;
    const unsigned short* wp = W1t + ((size_t)((s * 25 + off) * 64)) * 64;
#pragma unroll
    for (int ks = 0; ks < 2; ++ks) {
      short8 bv = *(const short8*)(xp + ks * 32 + quad * 8);
      if (!valid) bv = (short8)0;
#pragma unroll
      for (int m = 0; m < 4; ++m) {
        short8 av = *(const short8*)(wp + (m * 16 + low4) * 64 + ks * 32 + quad * 8);
        acc[m] = MFMA16(av, bv, acc[m]);
      }
    }
  }

  if (half) {
#pragma unroll
    for (int m = 0; m < 4; ++m)
#pragma unroll
      for (int r = 0; r < 4; ++r)
        Hbuf[wsub][low4][m * 16 + quad * 4 + r] = acc[m][r];
  }
  __syncthreads();
  if (!half) {
    float ls = 0.f, ls2 = 0.f;
#pragma unroll
    for (int m = 0; m < 4; ++m)
#pragma unroll
      for (int r = 0; r < 4; ++r) {
        const int co = m * 16 + quad * 4 + r;
        float y = acc[m][r] + Hbuf[wsub][low4][co] + b1p[co];
        Yt[((size_t)((s * 8 + b) * 1024 + p)) * 64 + co] = f2bf(y);
        ls += y; ls2 += y * y;
      }
#pragma unroll
    for (int o = 1; o < 64; o <<= 1) {
      ls += __shfl_xor(ls, o, 64);
      ls2 += __shfl_xor(ls2, o, 64);
    }
    if (lane == 0) { red[0][wsub] = ls; red[1][wsub] = ls2; }
  }
  __syncthreads();
  if (threadIdx.x == 0) {
    atomicAdd(&stats[(s * 8 + b) * 2 + 0], red[0][0] + red[0][1]);
    atomicAdd(&stats[(s * 8 + b) * 2 + 1], red[1][0] + red[1][1]);
  }
}

// ---------------- final body (one stem): bid in [0,256) --------------------
__device__ __forceinline__ void final_body(char* ws, const float* b2p,
                                           float* out, int s, int bid)
{
  const int b = bid >> 5, pt = bid & 31;
  const int w = threadIdx.x >> 6, lane = threadIdx.x & 63;
  const int low4 = lane & 15, quad = lane >> 4;
  const int p2 = pt * 32 + (w & 1) * 16 + low4;
  const int nh0 = (w >> 1) * 64;

  const unsigned short* Yt = (const unsigned short*)(ws + O_YT);
  const unsigned short* LNW = (const unsigned short*)(ws + O_LNW);
  const unsigned short* LNB = (const unsigned short*)(ws + O_LNB);
  const unsigned short* W2b = (const unsigned short*)(ws + O_W2B);
  const float* stats = (const float*)(ws + O_STATS);

  const float inv = 1.0f / 65536.0f;
  const float mu = stats[(s * 8 + b) * 2 + 0] * inv;
  const float ms = stats[(s * 8 + b) * 2 + 1] * inv;
  const float rsig = rsqrtf(ms - mu * mu + 1e-5f);

  f4 acc[4];
#pragma unroll
  for (int m = 0; m < 4; ++m) acc[m] = (f4){0.f, 0.f, 0.f, 0.f};

#pragma unroll
  for (int ks = 0; ks < 2; ++ks) {
    size_t yo = ((size_t)((s * 8 + b) * 1024 + p2)) * 64 + ks * 32 + quad * 8;
    size_t lo = ((size_t)(s * 1024 + p2)) * 64 + ks * 32 + quad * 8;
    short8 yv = *(const short8*)(Yt + yo);
    short8 lw8 = *(const short8*)(LNW + lo);
    short8 lb8 = *(const short8*)(LNB + lo);
    short8 zv;
#pragma unroll
    for (int j = 0; j < 8; ++j) {
      float z = (bf2f((unsigned short)yv[j]) - mu) * rsig * bf2f((unsigned short)lw8[j]) +
                bf2f((unsigned short)lb8[j]);
      zv[j] = (short)f2bf(fmaxf(z, 0.f));
    }
#pragma unroll
    for (int m = 0; m < 4; ++m) {
      short8 a = *(const short8*)(W2b + ((size_t)(s * 128 + nh0 + m * 16 + low4)) * 64 + ks * 32 + quad * 8);
      acc[m] = MFMA16(a, zv, acc[m]);
    }
  }
#pragma unroll
  for (int m = 0; m < 4; ++m)
#pragma unroll
    for (int r = 0; r < 4; ++r) {
      const int nh = nh0 + m * 16 + quad * 4 + r;
      out[((size_t)((s * 8 + b) * 128 + nh)) * 1024 + p2] = acc[m][r] + b2p[nh];
    }
}

// ============================================================================
// K4: conv5-spatial (0..255) ∪ conv5-channel (256..511) -- perfect 2/CU.
// ============================================================================
__global__ __launch_bounds__(256) void k4_conv5(
    char* __restrict__ ws, const float* __restrict__ sb1,
    const float* __restrict__ cb1)
{
  if (blockIdx.x < 256) conv5_body(ws, sb1, 0, blockIdx.x);
  else                  conv5_body(ws, cb1, 1, blockIdx.x - 256);
}

// ============================================================================
// K5: final-spatial (0..255) ∪ final-channel (256..511) -- perfect 2/CU.
// ============================================================================
__global__ __launch_bounds__(256) void k5_final(
    char* __restrict__ ws, const float* __restrict__ sb2,
    const float* __restrict__ cb2, float* __restrict__ out)
{
  if (blockIdx.x < 256) final_body(ws, sb2, out, 0, blockIdx.x);
  else                  final_body(ws, cb2, out, 1, blockIdx.x - 256);
}

extern "C" void kernel_launch(void* const* d_in, const int* in_sizes, int n_in,
                              void* d_out, int out_size, void* d_ws, size_t ws_size,
                              hipStream_t stream)
{
  const float* q    = (const float*)d_in[0];
  const float* keys = (const float*)d_in[1];
  const float* vals = (const float*)d_in[2];
  const float* sw1  = (const float*)d_in[3];
  const float* sb1  = (const float*)d_in[4];
  const float* slnw = (const float*)d_in[5];
  const float* slnb = (const float*)d_in[6];
  const float* sw2  = (const float*)d_in[7];
  const float* sb2  = (const float*)d_in[8];
  const float* cw1  = (const float*)d_in[9];
  const float* cb1  = (const float*)d_in[10];
  const float* clnw = (const float*)d_in[11];
  const float* clnb = (const float*)d_in[12];
  const float* cw2  = (const float*)d_in[13];
  const float* cb2  = (const float*)d_in[14];
  char* ws = (char*)d_ws;

  k1_prep<<<3232, 256, 0, stream>>>(q, keys, vals, sw1, slnw, slnb, sw2,
                                    cw1, clnw, clnb, cw2, ws);
  k2_soft_spat<<<544, 256, 0, stream>>>(ws);
  k3_chanB_fin<<<640, 256, 0, stream>>>(vals, ws);
  k4_conv5<<<512, 256, 0, stream>>>(ws, sb1, cb1);
  k5_final<<<512, 256, 0, stream>>>(ws, sb2, cb2, (float*)d_out);
}